// Round 9
// baseline (616.320 us; speedup 1.0000x reference)
//
#include <hip/hip_runtime.h>
#include <math.h>

#define NN    50000
#define MP    50048    // padded rows (782*64)
#define NEDGE 250000
#define NHOPE 125000
#define ETOT  375000
#define NRELS 500
#define BATCH 65536
#define LB1   6250     // light blocks (8 waves each -> 50000 waves)
#define HBMAX 5769     // max heavy nodes (deg>64): 375000/65

typedef __attribute__((ext_vector_type(8))) short bf16x8;
typedef __attribute__((ext_vector_type(4))) float f32x4;

__device__ __forceinline__ unsigned short bf16rne(float f) {
  unsigned u = __float_as_uint(f);
  unsigned r = (u + 0x7FFFu + ((u >> 16) & 1u)) >> 16;
  return (unsigned short)r;
}
__device__ __forceinline__ float b2f(unsigned short u) {
  return __uint_as_float(((unsigned)u) << 16);
}

struct GJob {
  const unsigned short* B;   // 208 x KP bf16
  float* Cf;                 // f32 out (ld 200) or null
  unsigned short* Cbf;       // bf16 out (ld 200) or null
  const float* a2;           // 200 floats or null
  float* dot;                // per-row scalar(s) or null
  int dotmode;               // 1 = split at 100 (two heads), 2 = single sum
};

// ---------------- l2norm -> bf16 padded (MP x 128) ----------------
__global__ __launch_bounds__(256) void l2norm_bf16(const float* __restrict__ in,
                                                   unsigned short* __restrict__ out) {
  int row  = blockIdx.x * 4 + (threadIdx.x >> 6);
  int lane = threadIdx.x & 63;
  if (row >= MP) return;
  unsigned short* o = out + (size_t)row * 128;
  if (row >= NN) { o[lane] = 0; o[lane + 64] = 0; return; }
  const float* r = in + (size_t)row * 100;
  float v0 = r[lane];
  float v1 = (lane + 64 < 100) ? r[lane + 64] : 0.f;
  float ss = v0 * v0 + v1 * v1;
  #pragma unroll
  for (int off = 1; off < 64; off <<= 1) ss += __shfl_xor(ss, off);
  float inv = 1.f / fmaxf(sqrtf(ss), 1e-12f);
  o[lane] = bf16rne(v0 * inv);
  o[lane + 64] = (lane + 64 < 100) ? bf16rne(v1 * inv) : (unsigned short)0;
}

// ---------------- multi-job bf16 MFMA GEMM, 16 rows/wave, LDS-coalesced epilogue ----------------
template<int KP>
__global__ __launch_bounds__(256) void gemm_multi(const unsigned short* __restrict__ A,
                                                  GJob j0, GJob j1, GJob j2, int M) {
  __shared__ float clds[4][16][208];
  GJob jb = (blockIdx.y == 0) ? j0 : ((blockIdx.y == 1) ? j1 : j2);
  int wv = threadIdx.x >> 6, lane = threadIdx.x & 63;
  int rbw = blockIdx.x * 64 + wv * 16;
  int rl = lane & 15;
  int kq = (lane >> 4) * 8;
  const unsigned short* ap = A + (size_t)(rbw + rl) * KP + kq;
  const unsigned short* bp = jb.B + (size_t)rl * KP + kq;
  f32x4 acc[13];
  #pragma unroll
  for (int t = 0; t < 13; ++t) acc[t] = (f32x4){0.f, 0.f, 0.f, 0.f};
  #pragma unroll 2
  for (int ks = 0; ks < KP; ks += 32) {
    bf16x8 a0 = *(const bf16x8*)(ap + ks);
    #pragma unroll
    for (int t = 0; t < 13; ++t) {
      bf16x8 b = *(const bf16x8*)(bp + (size_t)t * 16 * KP + ks);
      acc[t] = __builtin_amdgcn_mfma_f32_16x16x32_bf16(a0, b, acc[t], 0, 0, 0);
    }
  }
  int rg = (lane >> 4) * 4;
  if (jb.dot) {
    float p0[4] = {0.f, 0.f, 0.f, 0.f}, p1[4] = {0.f, 0.f, 0.f, 0.f};
    #pragma unroll
    for (int t = 0; t < 13; ++t) {
      int col = t * 16 + rl;
      float av = (col < 200) ? jb.a2[col] : 0.f;
      bool lo = (col < 100);
      #pragma unroll
      for (int g = 0; g < 4; ++g) {
        float v = acc[t][g] * av;
        if (lo) p0[g] += v; else p1[g] += v;
      }
    }
    #pragma unroll
    for (int off = 1; off < 16; off <<= 1) {
      #pragma unroll
      for (int g = 0; g < 4; ++g) {
        p0[g] += __shfl_xor(p0[g], off);
        p1[g] += __shfl_xor(p1[g], off);
      }
    }
    if (rl == 0) {
      #pragma unroll
      for (int g = 0; g < 4; ++g) {
        int row = rbw + rg + g;
        if (row < M) {
          if (jb.dotmode == 1) { jb.dot[row * 2] = p0[g]; jb.dot[row * 2 + 1] = p1[g]; }
          else                 { jb.dot[row] = p0[g] + p1[g]; }
        }
      }
    }
  }
  if (jb.Cf || jb.Cbf) {
    #pragma unroll
    for (int t = 0; t < 13; ++t) {
      #pragma unroll
      for (int g = 0; g < 4; ++g)
        clds[wv][rg + g][t * 16 + rl] = acc[t][g];
    }
    __syncthreads();
    #pragma unroll
    for (int i = 0; i < 13; ++i) {
      int idx = i * 64 + lane;       // [0, 832); 800 valid float4 slots
      if (idx < 800) {
        int r = idx / 50, cw = idx - r * 50;
        float4 v = *(const float4*)&clds[wv][r][cw * 4];
        int grow = rbw + r;
        if (grow < M) {
          if (jb.Cf) {
            *(float4*)(jb.Cf + (size_t)grow * 200 + cw * 4) = v;
          } else {
            ushort4 o = {bf16rne(v.x), bf16rne(v.y), bf16rne(v.z), bf16rne(v.w)};
            *(ushort4*)(jb.Cbf + (size_t)grow * 200 + cw * 4) = o;
          }
        }
      }
    }
  }
}

// ---------------- weight conversion to bf16 k-major padded ----------------
__global__ __launch_bounds__(256) void convB1(const float* __restrict__ ah, int koff,
                                              unsigned short* __restrict__ dst) {
  int idx = blockIdx.x * 256 + threadIdx.x;
  if (idx >= 208 * 128) return;
  int j = idx >> 7, k = idx & 127;
  float v = 0.f;
  if (j < 200 && k < 100) {
    const float* s = ah + ((j < 100) ? 0 : 30000) + (j % 100) * 300 + koff;
    v = s[k];
  }
  dst[idx] = bf16rne(v);
}

__global__ __launch_bounds__(256) void convBg(const float* __restrict__ src, int wsj, int wsk,
                                              int rows, int K, int Kp,
                                              unsigned short* __restrict__ dst) {
  int idx = blockIdx.x * 256 + threadIdx.x;
  if (idx >= 208 * Kp) return;
  int j = idx / Kp, k = idx - j * Kp;
  float v = (j < rows && k < K) ? src[(size_t)j * wsj + (size_t)k * wsk] : 0.f;
  dst[idx] = bf16rne(v);
}

// ---------------- f32 GEMM (small, rel matrices) ----------------
__global__ __launch_bounds__(256) void gemm2_f32(const float* __restrict__ A, int M, int Kd, int lda,
                                                 const float* __restrict__ W, int wsj, int wsk,
                                                 float* __restrict__ C, int ldc, int Ncols, int col0) {
  __shared__ float As[16][132];
  __shared__ float Bs[16][68];
  int tid = threadIdx.x;
  int tx = tid & 15, ty = tid >> 4;
  int row0 = blockIdx.y * 128;
  int colb = blockIdx.x * 64;
  float acc[8][4];
  #pragma unroll
  for (int i = 0; i < 8; ++i)
    #pragma unroll
    for (int j = 0; j < 4; ++j) acc[i][j] = 0.f;
  for (int kt = 0; kt < Kd; kt += 16) {
    #pragma unroll
    for (int l = 0; l < 8; ++l) {
      int idx = tid + l * 256;
      int m = idx >> 4, k = idx & 15;
      int gm = row0 + m, gk = kt + k;
      As[k][m] = (gm < M && gk < Kd) ? A[(size_t)gm * lda + gk] : 0.f;
    }
    #pragma unroll
    for (int l = 0; l < 4; ++l) {
      int idx = tid + l * 256;
      int j = idx >> 4, k = idx & 15;
      int gj = colb + j, gk = kt + k;
      Bs[k][j] = (gj < Ncols && gk < Kd) ? W[(size_t)gj * wsj + (size_t)gk * wsk] : 0.f;
    }
    __syncthreads();
    #pragma unroll
    for (int k = 0; k < 16; ++k) {
      float4 bv = *(const float4*)&Bs[k][tx * 4];
      float4 a0 = *(const float4*)&As[k][ty * 8];
      float4 a1 = *(const float4*)&As[k][ty * 8 + 4];
      float av[8] = {a0.x, a0.y, a0.z, a0.w, a1.x, a1.y, a1.z, a1.w};
      float bb[4] = {bv.x, bv.y, bv.z, bv.w};
      #pragma unroll
      for (int i = 0; i < 8; ++i)
        #pragma unroll
        for (int j = 0; j < 4; ++j)
          acc[i][j] += av[i] * bb[j];
    }
    __syncthreads();
  }
  int gj0 = colb + tx * 4;
  #pragma unroll
  for (int i = 0; i < 8; ++i) {
    int gm = row0 + ty * 8 + i;
    if (gm >= M) continue;
    float* cp = C + (size_t)gm * ldc + col0;
    #pragma unroll
    for (int j = 0; j < 4; ++j) if (gj0 + j < Ncols) cp[gj0 + j] = acc[i][j];
  }
}

// ---------------- per-row dots (rel rows only) ----------------
__global__ __launch_bounds__(256) void dot2h(const float* __restrict__ P, const float* __restrict__ a2,
                                             float* __restrict__ outp, int M) {
  int row  = blockIdx.x * 4 + (threadIdx.x >> 6);
  int lane = threadIdx.x & 63;
  if (row >= M) return;
  const float* pr = P + (size_t)row * 200;
  float s0 = 0.f, s1 = 0.f;
  for (int k = lane; k < 100; k += 64) {
    s0 += pr[k] * a2[k];
    s1 += pr[100 + k] * a2[100 + k];
  }
  #pragma unroll
  for (int off = 1; off < 64; off <<= 1) { s0 += __shfl_xor(s0, off); s1 += __shfl_xor(s1, off); }
  if (lane == 0) { outp[row * 2] = s0; outp[row * 2 + 1] = s1; }
}

__global__ __launch_bounds__(256) void dot1(const float* __restrict__ P, const float* __restrict__ a2,
                                            float* __restrict__ outp, int M) {
  int row  = blockIdx.x * 4 + (threadIdx.x >> 6);
  int lane = threadIdx.x & 63;
  if (row >= M) return;
  const float* pr = P + (size_t)row * 200;
  float s = 0.f;
  for (int k = lane; k < 200; k += 64) s += pr[k] * a2[k];
  #pragma unroll
  for (int off = 1; off < 64; off <<= 1) s += __shfl_xor(s, off);
  if (lane == 0) outp[row] = s;
}

// ---------------- CSR build ----------------
__global__ __launch_bounds__(256) void histk(const int* __restrict__ el, const int* __restrict__ tin,
                                             int* __restrict__ deg) {
  int i = blockIdx.x * 256 + threadIdx.x;
  if (i >= ETOT) return;
  int e0 = (i < NEDGE) ? el[i] : tin[(size_t)(i - NEDGE) * 4 + 3];
  atomicAdd(&deg[e0], 1);
}

__global__ __launch_bounds__(256) void scanA(const int* __restrict__ deg, int* __restrict__ bsum, int n) {
  __shared__ int s[256];
  int t = threadIdx.x;
  int i = blockIdx.x * 256 + t;
  s[t] = (i < n) ? deg[i] : 0;
  __syncthreads();
  for (int off = 128; off > 0; off >>= 1) {
    if (t < off) s[t] += s[t + off];
    __syncthreads();
  }
  if (t == 0) bsum[blockIdx.x] = s[0];
}

__global__ __launch_bounds__(256) void scanB(int* __restrict__ bsum, int nb) {
  __shared__ int s[256];
  int t = threadIdx.x;
  int v = (t < nb) ? bsum[t] : 0;
  s[t] = v;
  __syncthreads();
  for (int off = 1; off < 256; off <<= 1) {
    int add = (t >= off) ? s[t - off] : 0;
    __syncthreads();
    s[t] += add;
    __syncthreads();
  }
  if (t < nb) bsum[t] = s[t] - v;  // exclusive
}

__global__ __launch_bounds__(256) void scanC(const int* __restrict__ deg, const int* __restrict__ bsum,
                                             int* __restrict__ offs, int* __restrict__ pos, int n, int total) {
  __shared__ int s[256];
  int t = threadIdx.x;
  int i = blockIdx.x * 256 + t;
  int v = (i < n) ? deg[i] : 0;
  s[t] = v;
  __syncthreads();
  for (int off = 1; off < 256; off <<= 1) {
    int add = (t >= off) ? s[t - off] : 0;
    __syncthreads();
    s[t] += add;
    __syncthreads();
  }
  if (i < n) {
    int e = bsum[blockIdx.x] + s[t] - v;
    offs[i] = e;
    pos[i]  = e;
  }
  if (i == 0) offs[n] = total;
}

__global__ __launch_bounds__(256) void scatterk(const int* __restrict__ el, const int* __restrict__ et,
                                                const int* __restrict__ tin,
                                                int* __restrict__ pos, int2* __restrict__ edata) {
  int i = blockIdx.x * 256 + threadIdx.x;
  if (i >= ETOT) return;
  int e0, e1, t1, t2f;
  if (i < NEDGE) {
    e0 = el[i]; e1 = el[NEDGE + i]; t1 = et[i]; t2f = 0;
  } else {
    const int* q = tin + (size_t)(i - NEDGE) * 4;
    e0 = q[3]; e1 = q[0]; t1 = q[1]; t2f = q[2] + 1;
  }
  int slot = atomicAdd(&pos[e0], 1);
  edata[slot] = make_int2(e1 | (t1 << 16), t2f);
}

// wave-aggregated list append
__global__ __launch_bounds__(256) void buildLists(const int* __restrict__ offs,
                                                  int* __restrict__ lightL, int* __restrict__ heavyL,
                                                  int* __restrict__ cnts) {
  int i = blockIdx.x * 256 + threadIdx.x;
  int lane = threadIdx.x & 63;
  bool valid = (i < NN);
  int d = valid ? (offs[i + 1] - offs[i]) : 0;
  bool heavy = valid && (d > 64);
  bool light = valid && (d <= 64);
  unsigned long long mh = __ballot(heavy);
  unsigned long long ml = __ballot(light);
  unsigned long long below = (1ULL << lane) - 1ULL;
  int bh = 0, bl = 0;
  if (lane == 0) {
    if (mh) bh = atomicAdd(&cnts[1], __popcll(mh));
    if (ml) bl = atomicAdd(&cnts[0], __popcll(ml));
  }
  bh = __shfl(bh, 0);
  bl = __shfl(bl, 0);
  if (heavy) heavyL[bh + __popcll(mh & below)] = i;
  if (light) lightL[bl + __popcll(ml & below)] = i;
}

// ---------------- merged layer-1 gather (heavy-first), vectorized lanes ----------------
// lane l<50 owns cols 4l..4l+3 (head0 for l<25, head1 for l>=25)
__global__ __launch_bounds__(512) void gather1M(const int* __restrict__ lightL, const int* __restrict__ heavyL,
    const int* __restrict__ cnts, const int* __restrict__ offs, const int2* __restrict__ edata,
    const float* __restrict__ srcp, const unsigned short* __restrict__ dstb, const float* __restrict__ relp,
    const float* __restrict__ ssrc, const float* __restrict__ sdst, const float* __restrict__ srel,
    unsigned short* __restrict__ xbf) {
  __shared__ float part[8][208];
  int w = threadIdx.x >> 6, lane = threadIdx.x & 63;
  bool act = lane < 50;
  int cb = lane * 4;
  float a0 = 0.f, a1 = 0.f, a2v = 0.f, a3 = 0.f, rs0 = 0.f, rs1 = 0.f;
  float s00, s01;
  bool hd0 = (cb < 100);
  auto edgeop = [&](int2 ed) {
    unsigned w0 = (unsigned)ed.x;
    int e1 = (int)(w0 & 0xFFFFu);
    int t1 = (int)(w0 >> 16);
    int t2f = ed.y;
    float2 sd = *(const float2*)(sdst + e1 * 2);
    float p0 = s00 + sd.x + srel[t1 * 2];
    float p1 = s01 + sd.y + srel[t1 * 2 + 1];
    float m0 = 0.f, m1 = 0.f, m2 = 0.f, m3 = 0.f;
    if (act) {
      ushort4 dv = *(const ushort4*)(dstb + (size_t)e1 * 200 + cb);
      float4 r1v = *(const float4*)(relp + (size_t)t1 * 200 + cb);
      m0 = b2f(dv.x) + r1v.x;
      m1 = b2f(dv.y) + r1v.y;
      m2 = b2f(dv.z) + r1v.z;
      m3 = b2f(dv.w) + r1v.w;
    }
    if (t2f) {
      int t2 = t2f - 1;
      p0 += srel[t2 * 2]; p1 += srel[t2 * 2 + 1];
      if (act) {
        float4 r2v = *(const float4*)(relp + (size_t)t2 * 200 + cb);
        m0 += r2v.x; m1 += r2v.y; m2 += r2v.z; m3 += r2v.w;
      }
    }
    p0 = (p0 > 0.f) ? p0 : 0.2f * p0;
    p1 = (p1 > 0.f) ? p1 : 0.2f * p1;
    float ee0 = __expf(-p0), ee1 = __expf(-p1);
    rs0 += ee0; rs1 += ee1;
    float ee = hd0 ? ee0 : ee1;
    a0 += ee * m0; a1 += ee * m1; a2v += ee * m2; a3 += ee * m3;
  };
  if (blockIdx.x < HBMAX) {
    int hidx = blockIdx.x;
    if (hidx >= cnts[1]) return;
    int node = heavyL[hidx];
    int s = offs[node], e = offs[node + 1];
    s00 = ssrc[node * 2]; s01 = ssrc[node * 2 + 1];
    int q = s + w;
    for (; q + 8 < e; q += 16) { edgeop(edata[q]); edgeop(edata[q + 8]); }
    if (q < e) edgeop(edata[q]);
    if (act) { part[w][cb] = a0; part[w][cb + 1] = a1; part[w][cb + 2] = a2v; part[w][cb + 3] = a3; }
    if (lane == 0) { part[w][200] = rs0; part[w][201] = rs1; }
    __syncthreads();
    int t = threadIdx.x;
    if (t < 224) {
      unsigned short outv = 0;
      if (t < 200) {
        float a = 0.f, r0 = 0.f, r1 = 0.f;
        #pragma unroll
        for (int wv = 0; wv < 8; ++wv) { a += part[wv][t]; r0 += part[wv][200]; r1 += part[wv][201]; }
        float inv = (t < 100) ? 1.f / r0 : 1.f / r1;
        float v = srcp[(size_t)node * 200 + t] + a * inv;
        v = (v > 0.f) ? v : expm1f(v);
        outv = bf16rne(v);
      }
      xbf[(size_t)node * 224 + t] = outv;
    }
    return;
  }
  int widx = (blockIdx.x - HBMAX) * 8 + w;
  if (widx >= cnts[0]) return;
  int node = lightL[widx];
  int s = offs[node], e = offs[node + 1];
  s00 = ssrc[node * 2]; s01 = ssrc[node * 2 + 1];
  int q = s;
  for (; q + 1 < e; q += 2) { edgeop(edata[q]); edgeop(edata[q + 1]); }
  if (q < e) edgeop(edata[q]);
  bool has = (e > s);
  unsigned short* xo = xbf + (size_t)node * 224;
  if (act) {
    float inv = has ? (hd0 ? 1.f / rs0 : 1.f / rs1) : 0.f;
    const float* sp = srcp + (size_t)node * 200 + cb;
    float4 sv = *(const float4*)sp;
    float v0 = has ? sv.x + a0 * inv : 0.f;
    float v1 = has ? sv.y + a1 * inv : 0.f;
    float v2 = has ? sv.z + a2v * inv : 0.f;
    float v3 = has ? sv.w + a3 * inv : 0.f;
    v0 = (v0 > 0.f) ? v0 : expm1f(v0);
    v1 = (v1 > 0.f) ? v1 : expm1f(v1);
    v2 = (v2 > 0.f) ? v2 : expm1f(v2);
    v3 = (v3 > 0.f) ? v3 : expm1f(v3);
    ushort4 ov = {bf16rne(v0), bf16rne(v1), bf16rne(v2), bf16rne(v3)};
    *(ushort4*)(xo + cb) = ov;
  } else if (lane < 56) {
    ushort4 z = {0, 0, 0, 0};
    *(ushort4*)(xo + cb) = z;
  }
}

// ---------------- merged layer-2 gather (heavy-first), vectorized lanes ----------------
__global__ __launch_bounds__(512) void gather2M(const int* __restrict__ lightL, const int* __restrict__ heavyL,
    const int* __restrict__ cnts, const int* __restrict__ offs, const int2* __restrict__ edata,
    const float* __restrict__ srcp, const unsigned short* __restrict__ dstb, const float* __restrict__ relp,
    const float* __restrict__ ssrc, const float* __restrict__ sdst, const float* __restrict__ srel,
    float* __restrict__ hout) {
  __shared__ float part[8][208];
  int w = threadIdx.x >> 6, lane = threadIdx.x & 63;
  bool act = lane < 50;
  int cb = lane * 4;
  float a0 = 0.f, a1 = 0.f, a2v = 0.f, a3 = 0.f, rs = 0.f;
  float s0s;
  auto edgeop = [&](int2 ed) {
    unsigned w0 = (unsigned)ed.x;
    int e1 = (int)(w0 & 0xFFFFu);
    int t1 = (int)(w0 >> 16);
    int t2f = ed.y;
    float p = s0s + sdst[e1] + srel[t1];
    float m0 = 0.f, m1 = 0.f, m2 = 0.f, m3 = 0.f;
    if (act) {
      ushort4 dv = *(const ushort4*)(dstb + (size_t)e1 * 200 + cb);
      float4 r1v = *(const float4*)(relp + (size_t)t1 * 200 + cb);
      m0 = b2f(dv.x) + r1v.x;
      m1 = b2f(dv.y) + r1v.y;
      m2 = b2f(dv.z) + r1v.z;
      m3 = b2f(dv.w) + r1v.w;
    }
    if (t2f) {
      int t2 = t2f - 1;
      p += srel[t2];
      if (act) {
        float4 r2v = *(const float4*)(relp + (size_t)t2 * 200 + cb);
        m0 += r2v.x; m1 += r2v.y; m2 += r2v.z; m3 += r2v.w;
      }
    }
    p = (p > 0.f) ? p : 0.2f * p;
    float ee = __expf(-p);
    rs += ee;
    a0 += ee * m0; a1 += ee * m1; a2v += ee * m2; a3 += ee * m3;
  };
  if (blockIdx.x < HBMAX) {
    int hidx = blockIdx.x;
    if (hidx >= cnts[1]) return;
    int node = heavyL[hidx];
    int s = offs[node], e = offs[node + 1];
    s0s = ssrc[node];
    int q = s + w;
    for (; q + 8 < e; q += 16) { edgeop(edata[q]); edgeop(edata[q + 8]); }
    if (q < e) edgeop(edata[q]);
    if (act) { part[w][cb] = a0; part[w][cb + 1] = a1; part[w][cb + 2] = a2v; part[w][cb + 3] = a3; }
    if (lane == 0) part[w][200] = rs;
    __syncthreads();
    int t = threadIdx.x;
    if (t < 200) {
      float a = 0.f, r = 0.f;
      #pragma unroll
      for (int wv = 0; wv < 8; ++wv) { a += part[wv][t]; r += part[wv][200]; }
      float v = srcp[(size_t)node * 200 + t] + a / r;
      hout[(size_t)node * 200 + t] = (v > 0.f) ? v : expm1f(v);
    }
    return;
  }
  int widx = (blockIdx.x - HBMAX) * 8 + w;
  if (widx >= cnts[0]) return;
  int node = lightL[widx];
  int s = offs[node], e = offs[node + 1];
  s0s = ssrc[node];
  int q = s;
  for (; q + 1 < e; q += 2) { edgeop(edata[q]); edgeop(edata[q + 1]); }
  if (q < e) edgeop(edata[q]);
  if (!act) return;
  bool has = (e > s);
  float inv = has ? 1.f / rs : 0.f;
  const float* sp = srcp + (size_t)node * 200 + cb;
  float4 sv = *(const float4*)sp;
  float v0 = has ? sv.x + a0 * inv : 0.f;
  float v1 = has ? sv.y + a1 * inv : 0.f;
  float v2 = has ? sv.z + a2v * inv : 0.f;
  float v3 = has ? sv.w + a3 * inv : 0.f;
  v0 = (v0 > 0.f) ? v0 : expm1f(v0);
  v1 = (v1 > 0.f) ? v1 : expm1f(v1);
  v2 = (v2 > 0.f) ? v2 : expm1f(v2);
  v3 = (v3 > 0.f) ? v3 : expm1f(v3);
  float4 ov = {v0, v1, v2, v3};
  *(float4*)(hout + (size_t)node * 200 + cb) = ov;
}

// ---------------- pad xbf rows [NN, MP) ----------------
__global__ __launch_bounds__(256) void padx(unsigned short* __restrict__ xbf) {
  int i = blockIdx.x * 256 + threadIdx.x;
  if (i < (MP - NN) * 224) xbf[(size_t)NN * 224 + i] = 0;
}

// ---------------- mask scatter ----------------
__global__ __launch_bounds__(256) void maskset(const int* __restrict__ bi, float* __restrict__ maskA) {
  int t = blockIdx.x * 256 + threadIdx.x;
  if (t < BATCH) maskA[bi[t * 3 + 2]] = 1.0f;
}

// ---------------- final: out = l2norm(xw + mask*h2), in place ----------------
__global__ __launch_bounds__(256) void finalk2(const float* __restrict__ xw, const float* __restrict__ h2,
                                               const float* __restrict__ maskA, float* __restrict__ out) {
  int row  = blockIdx.x * 4 + (threadIdx.x >> 6);
  int lane = threadIdx.x & 63;
  if (row >= NN) return;
  float m = maskA[row];
  const float* xr = xw + (size_t)row * 200;
  const float* hr = h2 + (size_t)row * 200;
  int c0 = lane, c1 = lane + 64, c2 = lane + 128, c3 = lane + 192;
  float v0 = xr[c0] + m * hr[c0];
  float v1 = xr[c1] + m * hr[c1];
  float v2 = xr[c2] + m * hr[c2];
  float v3 = (c3 < 200) ? xr[c3] + m * hr[c3] : 0.f;
  float ss = v0 * v0 + v1 * v1 + v2 * v2 + v3 * v3;
  #pragma unroll
  for (int off = 1; off < 64; off <<= 1) ss += __shfl_xor(ss, off);
  float inv = 1.f / fmaxf(sqrtf(ss), 1e-12f);
  float* o = out + (size_t)row * 200;
  o[c0] = v0 * inv; o[c1] = v1 * inv; o[c2] = v2 * inv;
  if (c3 < 200) o[c3] = v3 * inv;
}

extern "C" void kernel_launch(void* const* d_in, const int* in_sizes, int n_in,
                              void* d_out, int out_size, void* d_ws, size_t ws_size,
                              hipStream_t stream) {
  (void)in_sizes; (void)n_in; (void)out_size; (void)ws_size;
  const float* ent      = (const float*)d_in[0];
  const float* rel      = (const float*)d_in[1];
  const float* a_heads  = (const float*)d_in[3];
  const float* a2_heads = (const float*)d_in[4];
  const float* W_gat    = (const float*)d_in[5];
  const float* a_out    = (const float*)d_in[6];
  const float* a2_out   = (const float*)d_in[7];
  const float* W_ent    = (const float*)d_in[8];
  const int* edge_list  = (const int*)d_in[9];
  const int* edge_type  = (const int*)d_in[10];
  const int* tin        = (const int*)d_in[11];
  const int* binp       = (const int*)d_in[12];

  float* out    = (float*)d_out;
  float* outrel = out + 10000000;     // (500,200)

  float* ws    = (float*)d_ws;
  float* bufS  = ws;                               // 10M f32: srcp1 -> srcp2 -> h2
  unsigned short* dstD = (unsigned short*)(ws + 10000000); // NN*200 bf16 (dstp1 then dstp2)
  float* relp1 = ws + 15000000;       // 100k
  float* relp2 = ws + 15100000;       // 100k
  float* ssrc1 = ws + 15200000;       // N*2
  float* sdst1 = ws + 15300000;       // N*2
  float* s2src = ws + 15400000;       // N
  float* s2dst = ws + 15450000;       // N
  float* srel1 = ws + 15500000;       // 1000
  float* s2rel = ws + 15501000;       // 500
  float* maskA = ws + 15502000;       // N
  unsigned short* x0nbf = (unsigned short*)(ws + 15560000); // MP*128 bf16
  unsigned short* xbf   = (unsigned short*)(ws + 18800000); // MP*224 bf16
  unsigned short* B1s   = (unsigned short*)(ws + 24450000); // 208*128
  unsigned short* B1d   = (unsigned short*)(ws + 24470000);
  unsigned short* Bxw   = (unsigned short*)(ws + 24490000);
  unsigned short* B2s   = (unsigned short*)(ws + 24510000); // 208*224
  unsigned short* B2d   = (unsigned short*)(ws + 24540000);
  int* ibase  = (int*)(ws + 24600000);
  int* deg    = ibase;                // 50k
  int* offs   = ibase + 50000;        // 50k+1
  int* pos    = ibase + 100016;       // 50k
  int* bsum   = ibase + 150016;       // 256
  int* cnts   = ibase + 150272;       // 2 (+pad)
  int* lightL = ibase + 150280;       // 50k
  int* heavyL = ibase + 200280;       // 50k (+pad)
  int2* edata = (int2*)(ibase + 250288); // 375k int2

  hipMemsetAsync(deg,   0, (size_t)NN * 4, stream);
  hipMemsetAsync(maskA, 0, (size_t)NN * 4, stream);
  hipMemsetAsync(cnts,  0, 8, stream);

  l2norm_bf16<<<12512, 256, 0, stream>>>(ent, x0nbf);

  // CSR + lists
  histk<<<(ETOT + 255) / 256, 256, 0, stream>>>(edge_list, tin, deg);
  scanA<<<196, 256, 0, stream>>>(deg, bsum, NN);
  scanB<<<1, 256, 0, stream>>>(bsum, 196);
  scanC<<<196, 256, 0, stream>>>(deg, bsum, offs, pos, NN, ETOT);
  scatterk<<<(ETOT + 255) / 256, 256, 0, stream>>>(edge_list, edge_type, tin, pos, edata);
  buildLists<<<196, 256, 0, stream>>>(offs, lightL, heavyL, cnts);

  // weight conversion
  convB1<<<104, 256, 0, stream>>>(a_heads, 0,   B1s);
  convB1<<<104, 256, 0, stream>>>(a_heads, 100, B1d);
  convBg<<<104, 256, 0, stream>>>(W_ent, 1, 200, 200, 100, 128, Bxw);
  convBg<<<182, 256, 0, stream>>>(a_out,       600, 1, 200, 200, 224, B2s);
  convBg<<<182, 256, 0, stream>>>(a_out + 200, 600, 1, 200, 200, 224, B2d);

  // layer-1 projections + xw, one 3-job launch
  {
    GJob js = {B1s, bufS, nullptr, a2_heads, ssrc1, 1};
    GJob jd = {B1d, nullptr, dstD, a2_heads, sdst1, 1};
    GJob jx = {Bxw, out, nullptr, nullptr, nullptr, 0};
    dim3 g(782, 3);
    gemm_multi<128><<<g, 256, 0, stream>>>(x0nbf, js, jd, jx, NN);
  }

  // rel projections (f32, small) + rel dots
  dim3 g2(2, 4);
  gemm2_f32<<<g2, 256, 0, stream>>>(rel, NRELS, 100, 100, a_heads + 200,         300, 1, relp1, 200, 100, 0);
  gemm2_f32<<<g2, 256, 0, stream>>>(rel, NRELS, 100, 100, a_heads + 30000 + 200, 300, 1, relp1, 200, 100, 100);
  dot2h<<<125, 256, 0, stream>>>(relp1, a2_heads, srel1, NRELS);

  gather1M<<<HBMAX + LB1, 512, 0, stream>>>(lightL, heavyL, cnts, offs, edata,
                                            bufS, dstD, relp1, ssrc1, sdst1, srel1, xbf);
  padx<<<42, 256, 0, stream>>>(xbf);

  // layer-2 projections, one 2-job launch (overwrites bufS/dstD)
  {
    GJob js = {B2s, bufS, nullptr, a2_out, s2src, 2};
    GJob jd = {B2d, nullptr, dstD, a2_out, s2dst, 2};
    GJob jz = {B2s, nullptr, nullptr, nullptr, nullptr, 0};
    dim3 g(782, 2);
    gemm_multi<224><<<g, 256, 0, stream>>>(xbf, js, jd, jz, NN);
  }

  // out_relation_1, relp2, rel dot
  dim3 g3(4, 4);
  gemm2_f32<<<g3, 256, 0, stream>>>(rel, NRELS, 100, 100, W_gat, 1, 200, outrel, 200, 200, 0);
  gemm2_f32<<<g3, 256, 0, stream>>>(outrel, NRELS, 200, 200, a_out + 400, 600, 1, relp2, 200, 200, 0);
  dot1<<<125, 256, 0, stream>>>(relp2, a2_out, s2rel, NRELS);

  maskset<<<256, 256, 0, stream>>>(binp, maskA);

  gather2M<<<HBMAX + LB1, 512, 0, stream>>>(lightL, heavyL, cnts, offs, edata,
                                            bufS, dstD, relp2, s2src, s2dst, s2rel, bufS);

  finalk2<<<12500, 256, 0, stream>>>(out, bufS, maskA, out);
}

// Round 10
// 572.530 us; speedup vs baseline: 1.0765x; 1.0765x over previous
//
#include <hip/hip_runtime.h>
#include <math.h>

#define NN    50000
#define MP    50048    // padded rows (782*64)
#define NEDGE 250000
#define NHOPE 125000
#define ETOT  375000
#define NRELS 500
#define BATCH 65536
#define LB1   6250     // light blocks (8 waves each -> 50000 waves)
#define HBMAX 5769     // max heavy nodes (deg>64): 375000/65

typedef __attribute__((ext_vector_type(8))) short bf16x8;
typedef __attribute__((ext_vector_type(4))) float f32x4;

__device__ __forceinline__ unsigned short bf16rne(float f) {
  unsigned u = __float_as_uint(f);
  unsigned r = (u + 0x7FFFu + ((u >> 16) & 1u)) >> 16;
  return (unsigned short)r;
}
__device__ __forceinline__ float b2f(unsigned short u) {
  return __uint_as_float(((unsigned)u) << 16);
}

struct GJob {
  const unsigned short* B;   // 208 x KP bf16
  float* Cf;                 // f32 out (ld 200) or null
  unsigned short* Cbf;       // bf16 out (ld 200) or null
  const float* a2;           // 200 floats or null
  float* dot;                // per-row scalar(s) or null
  int dotmode;               // 1 = split at 100 (two heads), 2 = single sum
};

// ---------------- l2norm -> bf16 padded (MP x 128) ----------------
__global__ __launch_bounds__(256) void l2norm_bf16(const float* __restrict__ in,
                                                   unsigned short* __restrict__ out) {
  int row  = blockIdx.x * 4 + (threadIdx.x >> 6);
  int lane = threadIdx.x & 63;
  if (row >= MP) return;
  unsigned short* o = out + (size_t)row * 128;
  if (row >= NN) { o[lane] = 0; o[lane + 64] = 0; return; }
  const float* r = in + (size_t)row * 100;
  float v0 = r[lane];
  float v1 = (lane + 64 < 100) ? r[lane + 64] : 0.f;
  float ss = v0 * v0 + v1 * v1;
  #pragma unroll
  for (int off = 1; off < 64; off <<= 1) ss += __shfl_xor(ss, off);
  float inv = 1.f / fmaxf(sqrtf(ss), 1e-12f);
  o[lane] = bf16rne(v0 * inv);
  o[lane + 64] = (lane + 64 < 100) ? bf16rne(v1 * inv) : (unsigned short)0;
}

// ---------------- multi-job bf16 MFMA GEMM, LDS-staged B, LDS-coalesced epilogue ----------------
// B staged in k-chunks of 64 halves into [208][72]-short LDS (bank-skewed, 16B rows);
// same LDS reused as the [4][16][212]-f32 epilogue transpose buffer.
template<int KP>
__global__ __launch_bounds__(256) void gemm_multi(const unsigned short* __restrict__ A,
                                                  GJob j0, GJob j1, GJob j2, int M) {
  __shared__ __attribute__((aligned(16))) char smem[54272];
  unsigned short* shb = (unsigned short*)smem;
  float (*clds)[16][212] = (float (*)[16][212])smem;   // [4][16][212]
  GJob jb = (blockIdx.y == 0) ? j0 : ((blockIdx.y == 1) ? j1 : j2);
  int wv = threadIdx.x >> 6, lane = threadIdx.x & 63;
  int rbw = blockIdx.x * 64 + wv * 16;
  int rl = lane & 15;
  int kq = (lane >> 4) * 8;
  const unsigned short* ap = A + (size_t)(rbw + rl) * KP + kq;
  f32x4 acc[13];
  #pragma unroll
  for (int t = 0; t < 13; ++t) acc[t] = (f32x4){0.f, 0.f, 0.f, 0.f};
  constexpr int NST = (KP + 63) / 64;
  #pragma unroll
  for (int s = 0; s < NST; ++s) {
    const int ks0 = s * 64;
    const int sw  = (KP - ks0 >= 64) ? 64 : (KP - ks0);   // 64 or 32, folds per unrolled iter
    const int cpr = sw / 8;                                // float4 chunks per row
    __syncthreads();
    for (int idx = threadIdx.x; idx < 208 * cpr; idx += 256) {
      int row = idx / cpr, cw = idx - row * cpr;
      *(float4*)(shb + row * 72 + cw * 8) =
          *(const float4*)(jb.B + (size_t)row * KP + ks0 + cw * 8);
    }
    __syncthreads();
    for (int ksl = 0; ksl < sw; ksl += 32) {
      bf16x8 a0 = *(const bf16x8*)(ap + ks0 + ksl);
      const unsigned short* bl = shb + (size_t)rl * 72 + kq + ksl;
      #pragma unroll
      for (int t = 0; t < 13; ++t) {
        bf16x8 b = *(const bf16x8*)(bl + t * 16 * 72);
        acc[t] = __builtin_amdgcn_mfma_f32_16x16x32_bf16(a0, b, acc[t], 0, 0, 0);
      }
    }
  }
  int rg = (lane >> 4) * 4;
  if (jb.dot) {
    float p0[4] = {0.f, 0.f, 0.f, 0.f}, p1[4] = {0.f, 0.f, 0.f, 0.f};
    #pragma unroll
    for (int t = 0; t < 13; ++t) {
      int col = t * 16 + rl;
      float av = (col < 200) ? jb.a2[col] : 0.f;
      bool lo = (col < 100);
      #pragma unroll
      for (int g = 0; g < 4; ++g) {
        float v = acc[t][g] * av;
        if (lo) p0[g] += v; else p1[g] += v;
      }
    }
    #pragma unroll
    for (int off = 1; off < 16; off <<= 1) {
      #pragma unroll
      for (int g = 0; g < 4; ++g) {
        p0[g] += __shfl_xor(p0[g], off);
        p1[g] += __shfl_xor(p1[g], off);
      }
    }
    if (rl == 0) {
      #pragma unroll
      for (int g = 0; g < 4; ++g) {
        int row = rbw + rg + g;
        if (row < M) {
          if (jb.dotmode == 1) { jb.dot[row * 2] = p0[g]; jb.dot[row * 2 + 1] = p1[g]; }
          else                 { jb.dot[row] = p0[g] + p1[g]; }
        }
      }
    }
  }
  if (jb.Cf || jb.Cbf) {
    __syncthreads();   // all B ds_reads done before overwriting smem as clds
    #pragma unroll
    for (int t = 0; t < 13; ++t) {
      #pragma unroll
      for (int g = 0; g < 4; ++g)
        clds[wv][rg + g][t * 16 + rl] = acc[t][g];
    }
    __syncthreads();
    #pragma unroll
    for (int i = 0; i < 13; ++i) {
      int idx = i * 64 + lane;       // [0, 832); 800 valid float4 slots
      if (idx < 800) {
        int r = idx / 50, cw = idx - r * 50;
        float4 v = *(const float4*)&clds[wv][r][cw * 4];
        int grow = rbw + r;
        if (grow < M) {
          if (jb.Cf) {
            *(float4*)(jb.Cf + (size_t)grow * 200 + cw * 4) = v;
          } else {
            ushort4 o = {bf16rne(v.x), bf16rne(v.y), bf16rne(v.z), bf16rne(v.w)};
            *(ushort4*)(jb.Cbf + (size_t)grow * 200 + cw * 4) = o;
          }
        }
      }
    }
  }
}

// ---------------- weight conversion to bf16 k-major padded ----------------
__global__ __launch_bounds__(256) void convB1(const float* __restrict__ ah, int koff,
                                              unsigned short* __restrict__ dst) {
  int idx = blockIdx.x * 256 + threadIdx.x;
  if (idx >= 208 * 128) return;
  int j = idx >> 7, k = idx & 127;
  float v = 0.f;
  if (j < 200 && k < 100) {
    const float* s = ah + ((j < 100) ? 0 : 30000) + (j % 100) * 300 + koff;
    v = s[k];
  }
  dst[idx] = bf16rne(v);
}

__global__ __launch_bounds__(256) void convBg(const float* __restrict__ src, int wsj, int wsk,
                                              int rows, int K, int Kp,
                                              unsigned short* __restrict__ dst) {
  int idx = blockIdx.x * 256 + threadIdx.x;
  if (idx >= 208 * Kp) return;
  int j = idx / Kp, k = idx - j * Kp;
  float v = (j < rows && k < K) ? src[(size_t)j * wsj + (size_t)k * wsk] : 0.f;
  dst[idx] = bf16rne(v);
}

// ---------------- f32 GEMM (small, rel matrices) ----------------
__global__ __launch_bounds__(256) void gemm2_f32(const float* __restrict__ A, int M, int Kd, int lda,
                                                 const float* __restrict__ W, int wsj, int wsk,
                                                 float* __restrict__ C, int ldc, int Ncols, int col0) {
  __shared__ float As[16][132];
  __shared__ float Bs[16][68];
  int tid = threadIdx.x;
  int tx = tid & 15, ty = tid >> 4;
  int row0 = blockIdx.y * 128;
  int colb = blockIdx.x * 64;
  float acc[8][4];
  #pragma unroll
  for (int i = 0; i < 8; ++i)
    #pragma unroll
    for (int j = 0; j < 4; ++j) acc[i][j] = 0.f;
  for (int kt = 0; kt < Kd; kt += 16) {
    #pragma unroll
    for (int l = 0; l < 8; ++l) {
      int idx = tid + l * 256;
      int m = idx >> 4, k = idx & 15;
      int gm = row0 + m, gk = kt + k;
      As[k][m] = (gm < M && gk < Kd) ? A[(size_t)gm * lda + gk] : 0.f;
    }
    #pragma unroll
    for (int l = 0; l < 4; ++l) {
      int idx = tid + l * 256;
      int j = idx >> 4, k = idx & 15;
      int gj = colb + j, gk = kt + k;
      Bs[k][j] = (gj < Ncols && gk < Kd) ? W[(size_t)gj * wsj + (size_t)gk * wsk] : 0.f;
    }
    __syncthreads();
    #pragma unroll
    for (int k = 0; k < 16; ++k) {
      float4 bv = *(const float4*)&Bs[k][tx * 4];
      float4 a0 = *(const float4*)&As[k][ty * 8];
      float4 a1 = *(const float4*)&As[k][ty * 8 + 4];
      float av[8] = {a0.x, a0.y, a0.z, a0.w, a1.x, a1.y, a1.z, a1.w};
      float bb[4] = {bv.x, bv.y, bv.z, bv.w};
      #pragma unroll
      for (int i = 0; i < 8; ++i)
        #pragma unroll
        for (int j = 0; j < 4; ++j)
          acc[i][j] += av[i] * bb[j];
    }
    __syncthreads();
  }
  int gj0 = colb + tx * 4;
  #pragma unroll
  for (int i = 0; i < 8; ++i) {
    int gm = row0 + ty * 8 + i;
    if (gm >= M) continue;
    float* cp = C + (size_t)gm * ldc + col0;
    #pragma unroll
    for (int j = 0; j < 4; ++j) if (gj0 + j < Ncols) cp[gj0 + j] = acc[i][j];
  }
}

// ---------------- per-row dots (rel rows only) ----------------
__global__ __launch_bounds__(256) void dot2h(const float* __restrict__ P, const float* __restrict__ a2,
                                             float* __restrict__ outp, int M) {
  int row  = blockIdx.x * 4 + (threadIdx.x >> 6);
  int lane = threadIdx.x & 63;
  if (row >= M) return;
  const float* pr = P + (size_t)row * 200;
  float s0 = 0.f, s1 = 0.f;
  for (int k = lane; k < 100; k += 64) {
    s0 += pr[k] * a2[k];
    s1 += pr[100 + k] * a2[100 + k];
  }
  #pragma unroll
  for (int off = 1; off < 64; off <<= 1) { s0 += __shfl_xor(s0, off); s1 += __shfl_xor(s1, off); }
  if (lane == 0) { outp[row * 2] = s0; outp[row * 2 + 1] = s1; }
}

__global__ __launch_bounds__(256) void dot1(const float* __restrict__ P, const float* __restrict__ a2,
                                            float* __restrict__ outp, int M) {
  int row  = blockIdx.x * 4 + (threadIdx.x >> 6);
  int lane = threadIdx.x & 63;
  if (row >= M) return;
  const float* pr = P + (size_t)row * 200;
  float s = 0.f;
  for (int k = lane; k < 200; k += 64) s += pr[k] * a2[k];
  #pragma unroll
  for (int off = 1; off < 64; off <<= 1) s += __shfl_xor(s, off);
  if (lane == 0) outp[row] = s;
}

// ---------------- CSR build ----------------
__global__ __launch_bounds__(256) void histk(const int* __restrict__ el, const int* __restrict__ tin,
                                             int* __restrict__ deg) {
  int i = blockIdx.x * 256 + threadIdx.x;
  if (i >= ETOT) return;
  int e0 = (i < NEDGE) ? el[i] : tin[(size_t)(i - NEDGE) * 4 + 3];
  atomicAdd(&deg[e0], 1);
}

__global__ __launch_bounds__(256) void scanA(const int* __restrict__ deg, int* __restrict__ bsum, int n) {
  __shared__ int s[256];
  int t = threadIdx.x;
  int i = blockIdx.x * 256 + t;
  s[t] = (i < n) ? deg[i] : 0;
  __syncthreads();
  for (int off = 128; off > 0; off >>= 1) {
    if (t < off) s[t] += s[t + off];
    __syncthreads();
  }
  if (t == 0) bsum[blockIdx.x] = s[0];
}

__global__ __launch_bounds__(256) void scanB(int* __restrict__ bsum, int nb) {
  __shared__ int s[256];
  int t = threadIdx.x;
  int v = (t < nb) ? bsum[t] : 0;
  s[t] = v;
  __syncthreads();
  for (int off = 1; off < 256; off <<= 1) {
    int add = (t >= off) ? s[t - off] : 0;
    __syncthreads();
    s[t] += add;
    __syncthreads();
  }
  if (t < nb) bsum[t] = s[t] - v;  // exclusive
}

__global__ __launch_bounds__(256) void scanC(const int* __restrict__ deg, const int* __restrict__ bsum,
                                             int* __restrict__ offs, int* __restrict__ pos, int n, int total) {
  __shared__ int s[256];
  int t = threadIdx.x;
  int i = blockIdx.x * 256 + t;
  int v = (i < n) ? deg[i] : 0;
  s[t] = v;
  __syncthreads();
  for (int off = 1; off < 256; off <<= 1) {
    int add = (t >= off) ? s[t - off] : 0;
    __syncthreads();
    s[t] += add;
    __syncthreads();
  }
  if (i < n) {
    int e = bsum[blockIdx.x] + s[t] - v;
    offs[i] = e;
    pos[i]  = e;
  }
  if (i == 0) offs[n] = total;
}

__global__ __launch_bounds__(256) void scatterk(const int* __restrict__ el, const int* __restrict__ et,
                                                const int* __restrict__ tin,
                                                int* __restrict__ pos, int2* __restrict__ edata) {
  int i = blockIdx.x * 256 + threadIdx.x;
  if (i >= ETOT) return;
  int e0, e1, t1, t2f;
  if (i < NEDGE) {
    e0 = el[i]; e1 = el[NEDGE + i]; t1 = et[i]; t2f = 0;
  } else {
    const int* q = tin + (size_t)(i - NEDGE) * 4;
    e0 = q[3]; e1 = q[0]; t1 = q[1]; t2f = q[2] + 1;
  }
  int slot = atomicAdd(&pos[e0], 1);
  edata[slot] = make_int2(e1 | (t1 << 16), t2f);
}

// wave-aggregated list append
__global__ __launch_bounds__(256) void buildLists(const int* __restrict__ offs,
                                                  int* __restrict__ lightL, int* __restrict__ heavyL,
                                                  int* __restrict__ cnts) {
  int i = blockIdx.x * 256 + threadIdx.x;
  int lane = threadIdx.x & 63;
  bool valid = (i < NN);
  int d = valid ? (offs[i + 1] - offs[i]) : 0;
  bool heavy = valid && (d > 64);
  bool light = valid && (d <= 64);
  unsigned long long mh = __ballot(heavy);
  unsigned long long ml = __ballot(light);
  unsigned long long below = (1ULL << lane) - 1ULL;
  int bh = 0, bl = 0;
  if (lane == 0) {
    if (mh) bh = atomicAdd(&cnts[1], __popcll(mh));
    if (ml) bl = atomicAdd(&cnts[0], __popcll(ml));
  }
  bh = __shfl(bh, 0);
  bl = __shfl(bl, 0);
  if (heavy) heavyL[bh + __popcll(mh & below)] = i;
  if (light) lightL[bl + __popcll(ml & below)] = i;
}

// ---------------- merged layer-1 gather (heavy-first), vectorized lanes ----------------
// lane l<50 owns cols 4l..4l+3 (head0 for l<25, head1 for l>=25)
__global__ __launch_bounds__(512) void gather1M(const int* __restrict__ lightL, const int* __restrict__ heavyL,
    const int* __restrict__ cnts, const int* __restrict__ offs, const int2* __restrict__ edata,
    const float* __restrict__ srcp, const unsigned short* __restrict__ dstb, const float* __restrict__ relp,
    const float* __restrict__ ssrc, const float* __restrict__ sdst, const float* __restrict__ srel,
    unsigned short* __restrict__ xbf) {
  __shared__ float part[8][208];
  int w = threadIdx.x >> 6, lane = threadIdx.x & 63;
  bool act = lane < 50;
  int cb = lane * 4;
  float a0 = 0.f, a1 = 0.f, a2v = 0.f, a3 = 0.f, rs0 = 0.f, rs1 = 0.f;
  float s00, s01;
  bool hd0 = (cb < 100);
  auto edgeop = [&](int2 ed) {
    unsigned w0 = (unsigned)ed.x;
    int e1 = (int)(w0 & 0xFFFFu);
    int t1 = (int)(w0 >> 16);
    int t2f = ed.y;
    float2 sd = *(const float2*)(sdst + e1 * 2);
    float p0 = s00 + sd.x + srel[t1 * 2];
    float p1 = s01 + sd.y + srel[t1 * 2 + 1];
    float m0 = 0.f, m1 = 0.f, m2 = 0.f, m3 = 0.f;
    if (act) {
      ushort4 dv = *(const ushort4*)(dstb + (size_t)e1 * 200 + cb);
      float4 r1v = *(const float4*)(relp + (size_t)t1 * 200 + cb);
      m0 = b2f(dv.x) + r1v.x;
      m1 = b2f(dv.y) + r1v.y;
      m2 = b2f(dv.z) + r1v.z;
      m3 = b2f(dv.w) + r1v.w;
    }
    if (t2f) {
      int t2 = t2f - 1;
      p0 += srel[t2 * 2]; p1 += srel[t2 * 2 + 1];
      if (act) {
        float4 r2v = *(const float4*)(relp + (size_t)t2 * 200 + cb);
        m0 += r2v.x; m1 += r2v.y; m2 += r2v.z; m3 += r2v.w;
      }
    }
    p0 = (p0 > 0.f) ? p0 : 0.2f * p0;
    p1 = (p1 > 0.f) ? p1 : 0.2f * p1;
    float ee0 = __expf(-p0), ee1 = __expf(-p1);
    rs0 += ee0; rs1 += ee1;
    float ee = hd0 ? ee0 : ee1;
    a0 += ee * m0; a1 += ee * m1; a2v += ee * m2; a3 += ee * m3;
  };
  if (blockIdx.x < HBMAX) {
    int hidx = blockIdx.x;
    if (hidx >= cnts[1]) return;
    int node = heavyL[hidx];
    int s = offs[node], e = offs[node + 1];
    s00 = ssrc[node * 2]; s01 = ssrc[node * 2 + 1];
    int q = s + w;
    for (; q + 8 < e; q += 16) { edgeop(edata[q]); edgeop(edata[q + 8]); }
    if (q < e) edgeop(edata[q]);
    if (act) { part[w][cb] = a0; part[w][cb + 1] = a1; part[w][cb + 2] = a2v; part[w][cb + 3] = a3; }
    if (lane == 0) { part[w][200] = rs0; part[w][201] = rs1; }
    __syncthreads();
    int t = threadIdx.x;
    if (t < 224) {
      unsigned short outv = 0;
      if (t < 200) {
        float a = 0.f, r0 = 0.f, r1 = 0.f;
        #pragma unroll
        for (int wv = 0; wv < 8; ++wv) { a += part[wv][t]; r0 += part[wv][200]; r1 += part[wv][201]; }
        float inv = (t < 100) ? 1.f / r0 : 1.f / r1;
        float v = srcp[(size_t)node * 200 + t] + a * inv;
        v = (v > 0.f) ? v : expm1f(v);
        outv = bf16rne(v);
      }
      xbf[(size_t)node * 224 + t] = outv;
    }
    return;
  }
  int widx = (blockIdx.x - HBMAX) * 8 + w;
  if (widx >= cnts[0]) return;
  int node = lightL[widx];
  int s = offs[node], e = offs[node + 1];
  s00 = ssrc[node * 2]; s01 = ssrc[node * 2 + 1];
  int q = s;
  for (; q + 1 < e; q += 2) { edgeop(edata[q]); edgeop(edata[q + 1]); }
  if (q < e) edgeop(edata[q]);
  bool has = (e > s);
  unsigned short* xo = xbf + (size_t)node * 224;
  if (act) {
    float inv = has ? (hd0 ? 1.f / rs0 : 1.f / rs1) : 0.f;
    const float* sp = srcp + (size_t)node * 200 + cb;
    float4 sv = *(const float4*)sp;
    float v0 = has ? sv.x + a0 * inv : 0.f;
    float v1 = has ? sv.y + a1 * inv : 0.f;
    float v2 = has ? sv.z + a2v * inv : 0.f;
    float v3 = has ? sv.w + a3 * inv : 0.f;
    v0 = (v0 > 0.f) ? v0 : expm1f(v0);
    v1 = (v1 > 0.f) ? v1 : expm1f(v1);
    v2 = (v2 > 0.f) ? v2 : expm1f(v2);
    v3 = (v3 > 0.f) ? v3 : expm1f(v3);
    ushort4 ov = {bf16rne(v0), bf16rne(v1), bf16rne(v2), bf16rne(v3)};
    *(ushort4*)(xo + cb) = ov;
  } else if (lane < 56) {
    ushort4 z = {0, 0, 0, 0};
    *(ushort4*)(xo + cb) = z;
  }
}

// ---------------- merged layer-2 gather (heavy-first), vectorized lanes ----------------
__global__ __launch_bounds__(512) void gather2M(const int* __restrict__ lightL, const int* __restrict__ heavyL,
    const int* __restrict__ cnts, const int* __restrict__ offs, const int2* __restrict__ edata,
    const float* __restrict__ srcp, const unsigned short* __restrict__ dstb, const float* __restrict__ relp,
    const float* __restrict__ ssrc, const float* __restrict__ sdst, const float* __restrict__ srel,
    float* __restrict__ hout) {
  __shared__ float part[8][208];
  int w = threadIdx.x >> 6, lane = threadIdx.x & 63;
  bool act = lane < 50;
  int cb = lane * 4;
  float a0 = 0.f, a1 = 0.f, a2v = 0.f, a3 = 0.f, rs = 0.f;
  float s0s;
  auto edgeop = [&](int2 ed) {
    unsigned w0 = (unsigned)ed.x;
    int e1 = (int)(w0 & 0xFFFFu);
    int t1 = (int)(w0 >> 16);
    int t2f = ed.y;
    float p = s0s + sdst[e1] + srel[t1];
    float m0 = 0.f, m1 = 0.f, m2 = 0.f, m3 = 0.f;
    if (act) {
      ushort4 dv = *(const ushort4*)(dstb + (size_t)e1 * 200 + cb);
      float4 r1v = *(const float4*)(relp + (size_t)t1 * 200 + cb);
      m0 = b2f(dv.x) + r1v.x;
      m1 = b2f(dv.y) + r1v.y;
      m2 = b2f(dv.z) + r1v.z;
      m3 = b2f(dv.w) + r1v.w;
    }
    if (t2f) {
      int t2 = t2f - 1;
      p += srel[t2];
      if (act) {
        float4 r2v = *(const float4*)(relp + (size_t)t2 * 200 + cb);
        m0 += r2v.x; m1 += r2v.y; m2 += r2v.z; m3 += r2v.w;
      }
    }
    p = (p > 0.f) ? p : 0.2f * p;
    float ee = __expf(-p);
    rs += ee;
    a0 += ee * m0; a1 += ee * m1; a2v += ee * m2; a3 += ee * m3;
  };
  if (blockIdx.x < HBMAX) {
    int hidx = blockIdx.x;
    if (hidx >= cnts[1]) return;
    int node = heavyL[hidx];
    int s = offs[node], e = offs[node + 1];
    s0s = ssrc[node];
    int q = s + w;
    for (; q + 8 < e; q += 16) { edgeop(edata[q]); edgeop(edata[q + 8]); }
    if (q < e) edgeop(edata[q]);
    if (act) { part[w][cb] = a0; part[w][cb + 1] = a1; part[w][cb + 2] = a2v; part[w][cb + 3] = a3; }
    if (lane == 0) part[w][200] = rs;
    __syncthreads();
    int t = threadIdx.x;
    if (t < 200) {
      float a = 0.f, r = 0.f;
      #pragma unroll
      for (int wv = 0; wv < 8; ++wv) { a += part[wv][t]; r += part[wv][200]; }
      float v = srcp[(size_t)node * 200 + t] + a / r;
      hout[(size_t)node * 200 + t] = (v > 0.f) ? v : expm1f(v);
    }
    return;
  }
  int widx = (blockIdx.x - HBMAX) * 8 + w;
  if (widx >= cnts[0]) return;
  int node = lightL[widx];
  int s = offs[node], e = offs[node + 1];
  s0s = ssrc[node];
  int q = s;
  for (; q + 1 < e; q += 2) { edgeop(edata[q]); edgeop(edata[q + 1]); }
  if (q < e) edgeop(edata[q]);
  if (!act) return;
  bool has = (e > s);
  float inv = has ? 1.f / rs : 0.f;
  const float* sp = srcp + (size_t)node * 200 + cb;
  float4 sv = *(const float4*)sp;
  float v0 = has ? sv.x + a0 * inv : 0.f;
  float v1 = has ? sv.y + a1 * inv : 0.f;
  float v2 = has ? sv.z + a2v * inv : 0.f;
  float v3 = has ? sv.w + a3 * inv : 0.f;
  v0 = (v0 > 0.f) ? v0 : expm1f(v0);
  v1 = (v1 > 0.f) ? v1 : expm1f(v1);
  v2 = (v2 > 0.f) ? v2 : expm1f(v2);
  v3 = (v3 > 0.f) ? v3 : expm1f(v3);
  float4 ov = {v0, v1, v2, v3};
  *(float4*)(hout + (size_t)node * 200 + cb) = ov;
}

// ---------------- pad xbf rows [NN, MP) ----------------
__global__ __launch_bounds__(256) void padx(unsigned short* __restrict__ xbf) {
  int i = blockIdx.x * 256 + threadIdx.x;
  if (i < (MP - NN) * 224) xbf[(size_t)NN * 224 + i] = 0;
}

// ---------------- mask scatter ----------------
__global__ __launch_bounds__(256) void maskset(const int* __restrict__ bi, float* __restrict__ maskA) {
  int t = blockIdx.x * 256 + threadIdx.x;
  if (t < BATCH) maskA[bi[t * 3 + 2]] = 1.0f;
}

// ---------------- final: out = l2norm(xw + mask*h2), in place ----------------
__global__ __launch_bounds__(256) void finalk2(const float* __restrict__ xw, const float* __restrict__ h2,
                                               const float* __restrict__ maskA, float* __restrict__ out) {
  int row  = blockIdx.x * 4 + (threadIdx.x >> 6);
  int lane = threadIdx.x & 63;
  if (row >= NN) return;
  float m = maskA[row];
  const float* xr = xw + (size_t)row * 200;
  const float* hr = h2 + (size_t)row * 200;
  int c0 = lane, c1 = lane + 64, c2 = lane + 128, c3 = lane + 192;
  float v0 = xr[c0] + m * hr[c0];
  float v1 = xr[c1] + m * hr[c1];
  float v2 = xr[c2] + m * hr[c2];
  float v3 = (c3 < 200) ? xr[c3] + m * hr[c3] : 0.f;
  float ss = v0 * v0 + v1 * v1 + v2 * v2 + v3 * v3;
  #pragma unroll
  for (int off = 1; off < 64; off <<= 1) ss += __shfl_xor(ss, off);
  float inv = 1.f / fmaxf(sqrtf(ss), 1e-12f);
  float* o = out + (size_t)row * 200;
  o[c0] = v0 * inv; o[c1] = v1 * inv; o[c2] = v2 * inv;
  if (c3 < 200) o[c3] = v3 * inv;
}

extern "C" void kernel_launch(void* const* d_in, const int* in_sizes, int n_in,
                              void* d_out, int out_size, void* d_ws, size_t ws_size,
                              hipStream_t stream) {
  (void)in_sizes; (void)n_in; (void)out_size; (void)ws_size;
  const float* ent      = (const float*)d_in[0];
  const float* rel      = (const float*)d_in[1];
  const float* a_heads  = (const float*)d_in[3];
  const float* a2_heads = (const float*)d_in[4];
  const float* W_gat    = (const float*)d_in[5];
  const float* a_out    = (const float*)d_in[6];
  const float* a2_out   = (const float*)d_in[7];
  const float* W_ent    = (const float*)d_in[8];
  const int* edge_list  = (const int*)d_in[9];
  const int* edge_type  = (const int*)d_in[10];
  const int* tin        = (const int*)d_in[11];
  const int* binp       = (const int*)d_in[12];

  float* out    = (float*)d_out;
  float* outrel = out + 10000000;     // (500,200)

  float* ws    = (float*)d_ws;
  float* bufS  = ws;                               // 10M f32: srcp1 -> srcp2 -> h2
  unsigned short* dstD = (unsigned short*)(ws + 10000000); // NN*200 bf16 (dstp1 then dstp2)
  float* relp1 = ws + 15000000;       // 100k
  float* relp2 = ws + 15100000;       // 100k
  float* ssrc1 = ws + 15200000;       // N*2
  float* sdst1 = ws + 15300000;       // N*2
  float* s2src = ws + 15400000;       // N
  float* s2dst = ws + 15450000;       // N
  float* srel1 = ws + 15500000;       // 1000
  float* s2rel = ws + 15501000;       // 500
  float* maskA = ws + 15502000;       // N
  unsigned short* x0nbf = (unsigned short*)(ws + 15560000); // MP*128 bf16
  unsigned short* xbf   = (unsigned short*)(ws + 18800000); // MP*224 bf16
  unsigned short* B1s   = (unsigned short*)(ws + 24450000); // 208*128
  unsigned short* B1d   = (unsigned short*)(ws + 24470000);
  unsigned short* Bxw   = (unsigned short*)(ws + 24490000);
  unsigned short* B2s   = (unsigned short*)(ws + 24510000); // 208*224
  unsigned short* B2d   = (unsigned short*)(ws + 24540000);
  int* ibase  = (int*)(ws + 24600000);
  int* deg    = ibase;                // 50k
  int* offs   = ibase + 50000;        // 50k+1
  int* pos    = ibase + 100016;       // 50k
  int* bsum   = ibase + 150016;       // 256
  int* cnts   = ibase + 150272;       // 2 (+pad)
  int* lightL = ibase + 150280;       // 50k
  int* heavyL = ibase + 200280;       // 50k (+pad)
  int2* edata = (int2*)(ibase + 250288); // 375k int2

  hipMemsetAsync(deg,   0, (size_t)NN * 4, stream);
  hipMemsetAsync(maskA, 0, (size_t)NN * 4, stream);
  hipMemsetAsync(cnts,  0, 8, stream);

  l2norm_bf16<<<12512, 256, 0, stream>>>(ent, x0nbf);

  // CSR + lists
  histk<<<(ETOT + 255) / 256, 256, 0, stream>>>(edge_list, tin, deg);
  scanA<<<196, 256, 0, stream>>>(deg, bsum, NN);
  scanB<<<1, 256, 0, stream>>>(bsum, 196);
  scanC<<<196, 256, 0, stream>>>(deg, bsum, offs, pos, NN, ETOT);
  scatterk<<<(ETOT + 255) / 256, 256, 0, stream>>>(edge_list, edge_type, tin, pos, edata);
  buildLists<<<196, 256, 0, stream>>>(offs, lightL, heavyL, cnts);

  // weight conversion
  convB1<<<104, 256, 0, stream>>>(a_heads, 0,   B1s);
  convB1<<<104, 256, 0, stream>>>(a_heads, 100, B1d);
  convBg<<<104, 256, 0, stream>>>(W_ent, 1, 200, 200, 100, 128, Bxw);
  convBg<<<182, 256, 0, stream>>>(a_out,       600, 1, 200, 200, 224, B2s);
  convBg<<<182, 256, 0, stream>>>(a_out + 200, 600, 1, 200, 200, 224, B2d);

  // layer-1 projections + xw, one 3-job launch
  {
    GJob js = {B1s, bufS, nullptr, a2_heads, ssrc1, 1};
    GJob jd = {B1d, nullptr, dstD, a2_heads, sdst1, 1};
    GJob jx = {Bxw, out, nullptr, nullptr, nullptr, 0};
    dim3 g(782, 3);
    gemm_multi<128><<<g, 256, 0, stream>>>(x0nbf, js, jd, jx, NN);
  }

  // rel projections (f32, small) + rel dots
  dim3 g2(2, 4);
  gemm2_f32<<<g2, 256, 0, stream>>>(rel, NRELS, 100, 100, a_heads + 200,         300, 1, relp1, 200, 100, 0);
  gemm2_f32<<<g2, 256, 0, stream>>>(rel, NRELS, 100, 100, a_heads + 30000 + 200, 300, 1, relp1, 200, 100, 100);
  dot2h<<<125, 256, 0, stream>>>(relp1, a2_heads, srel1, NRELS);

  gather1M<<<HBMAX + LB1, 512, 0, stream>>>(lightL, heavyL, cnts, offs, edata,
                                            bufS, dstD, relp1, ssrc1, sdst1, srel1, xbf);
  padx<<<42, 256, 0, stream>>>(xbf);

  // layer-2 projections, one 2-job launch (overwrites bufS/dstD)
  {
    GJob js = {B2s, bufS, nullptr, a2_out, s2src, 2};
    GJob jd = {B2d, nullptr, dstD, a2_out, s2dst, 2};
    GJob jz = {B2s, nullptr, nullptr, nullptr, nullptr, 0};
    dim3 g(782, 2);
    gemm_multi<224><<<g, 256, 0, stream>>>(xbf, js, jd, jz, NN);
  }

  // out_relation_1, relp2, rel dot
  dim3 g3(4, 4);
  gemm2_f32<<<g3, 256, 0, stream>>>(rel, NRELS, 100, 100, W_gat, 1, 200, outrel, 200, 200, 0);
  gemm2_f32<<<g3, 256, 0, stream>>>(outrel, NRELS, 200, 200, a_out + 400, 600, 1, relp2, 200, 200, 0);
  dot1<<<125, 256, 0, stream>>>(relp2, a2_out, s2rel, NRELS);

  maskset<<<256, 256, 0, stream>>>(binp, maskA);

  gather2M<<<HBMAX + LB1, 512, 0, stream>>>(lightL, heavyL, cnts, offs, edata,
                                            bufS, dstD, relp2, s2src, s2dst, s2rel, bufS);

  finalk2<<<12500, 256, 0, stream>>>(out, bufS, maskA, out);
}

// Round 11
// 543.276 us; speedup vs baseline: 1.1345x; 1.0538x over previous
//
#include <hip/hip_runtime.h>
#include <math.h>

#define NN    50000
#define MP    50048    // padded rows (782*64)
#define NEDGE 250000
#define NHOPE 125000
#define ETOT  375000
#define NRELS 500
#define BATCH 65536
#define LB1   6250     // light blocks (8 waves each -> 50000 waves)
#define HBMAX 5769     // max heavy nodes (deg>64): 375000/65

typedef __attribute__((ext_vector_type(8))) short bf16x8;
typedef __attribute__((ext_vector_type(4))) float f32x4;

__device__ __forceinline__ unsigned short bf16rne(float f) {
  unsigned u = __float_as_uint(f);
  unsigned r = (u + 0x7FFFu + ((u >> 16) & 1u)) >> 16;
  return (unsigned short)r;
}
__device__ __forceinline__ float b2f(unsigned short u) {
  return __uint_as_float(((unsigned)u) << 16);
}

struct GJob {
  const unsigned short* B;   // 208 x KP bf16
  float* Cf;                 // f32 out (ld 200) or null
  unsigned short* Cbf;       // bf16 out (ld 200) or null
  const float* a2;           // 200 floats or null
  float* dot;                // per-row scalar(s) or null
  int dotmode;               // 1 = split at 100 (two heads), 2 = single sum
};

// ---------------- l2norm -> bf16 padded (MP x 128) ----------------
__global__ __launch_bounds__(256) void l2norm_bf16(const float* __restrict__ in,
                                                   unsigned short* __restrict__ out) {
  int row  = blockIdx.x * 4 + (threadIdx.x >> 6);
  int lane = threadIdx.x & 63;
  if (row >= MP) return;
  unsigned short* o = out + (size_t)row * 128;
  if (row >= NN) { o[lane] = 0; o[lane + 64] = 0; return; }
  const float* r = in + (size_t)row * 100;
  float v0 = r[lane];
  float v1 = (lane + 64 < 100) ? r[lane + 64] : 0.f;
  float ss = v0 * v0 + v1 * v1;
  #pragma unroll
  for (int off = 1; off < 64; off <<= 1) ss += __shfl_xor(ss, off);
  float inv = 1.f / fmaxf(sqrtf(ss), 1e-12f);
  o[lane] = bf16rne(v0 * inv);
  o[lane + 64] = (lane + 64 < 100) ? bf16rne(v1 * inv) : (unsigned short)0;
}

// ---------------- multi-job bf16 MFMA GEMM, LDS-staged B, LDS-coalesced epilogue ----------------
template<int KP>
__global__ __launch_bounds__(256) void gemm_multi(const unsigned short* __restrict__ A,
                                                  GJob j0, GJob j1, GJob j2, int M) {
  __shared__ __attribute__((aligned(16))) char smem[54272];
  unsigned short* shb = (unsigned short*)smem;
  float (*clds)[16][212] = (float (*)[16][212])smem;   // [4][16][212]
  GJob jb = (blockIdx.y == 0) ? j0 : ((blockIdx.y == 1) ? j1 : j2);
  int wv = threadIdx.x >> 6, lane = threadIdx.x & 63;
  int rbw = blockIdx.x * 64 + wv * 16;
  int rl = lane & 15;
  int kq = (lane >> 4) * 8;
  const unsigned short* ap = A + (size_t)(rbw + rl) * KP + kq;
  f32x4 acc[13];
  #pragma unroll
  for (int t = 0; t < 13; ++t) acc[t] = (f32x4){0.f, 0.f, 0.f, 0.f};
  constexpr int NST = (KP + 63) / 64;
  #pragma unroll
  for (int s = 0; s < NST; ++s) {
    const int ks0 = s * 64;
    const int sw  = (KP - ks0 >= 64) ? 64 : (KP - ks0);
    const int cpr = sw / 8;
    __syncthreads();
    for (int idx = threadIdx.x; idx < 208 * cpr; idx += 256) {
      int row = idx / cpr, cw = idx - row * cpr;
      *(float4*)(shb + row * 72 + cw * 8) =
          *(const float4*)(jb.B + (size_t)row * KP + ks0 + cw * 8);
    }
    __syncthreads();
    for (int ksl = 0; ksl < sw; ksl += 32) {
      bf16x8 a0 = *(const bf16x8*)(ap + ks0 + ksl);
      const unsigned short* bl = shb + (size_t)rl * 72 + kq + ksl;
      #pragma unroll
      for (int t = 0; t < 13; ++t) {
        bf16x8 b = *(const bf16x8*)(bl + t * 16 * 72);
        acc[t] = __builtin_amdgcn_mfma_f32_16x16x32_bf16(a0, b, acc[t], 0, 0, 0);
      }
    }
  }
  int rg = (lane >> 4) * 4;
  if (jb.dot) {
    float p0[4] = {0.f, 0.f, 0.f, 0.f}, p1[4] = {0.f, 0.f, 0.f, 0.f};
    #pragma unroll
    for (int t = 0; t < 13; ++t) {
      int col = t * 16 + rl;
      float av = (col < 200) ? jb.a2[col] : 0.f;
      bool lo = (col < 100);
      #pragma unroll
      for (int g = 0; g < 4; ++g) {
        float v = acc[t][g] * av;
        if (lo) p0[g] += v; else p1[g] += v;
      }
    }
    #pragma unroll
    for (int off = 1; off < 16; off <<= 1) {
      #pragma unroll
      for (int g = 0; g < 4; ++g) {
        p0[g] += __shfl_xor(p0[g], off);
        p1[g] += __shfl_xor(p1[g], off);
      }
    }
    if (rl == 0) {
      #pragma unroll
      for (int g = 0; g < 4; ++g) {
        int row = rbw + rg + g;
        if (row < M) {
          if (jb.dotmode == 1) { jb.dot[row * 2] = p0[g]; jb.dot[row * 2 + 1] = p1[g]; }
          else                 { jb.dot[row] = p0[g] + p1[g]; }
        }
      }
    }
  }
  if (jb.Cf || jb.Cbf) {
    __syncthreads();
    #pragma unroll
    for (int t = 0; t < 13; ++t) {
      #pragma unroll
      for (int g = 0; g < 4; ++g)
        clds[wv][rg + g][t * 16 + rl] = acc[t][g];
    }
    __syncthreads();
    #pragma unroll
    for (int i = 0; i < 13; ++i) {
      int idx = i * 64 + lane;
      if (idx < 800) {
        int r = idx / 50, cw = idx - r * 50;
        float4 v = *(const float4*)&clds[wv][r][cw * 4];
        int grow = rbw + r;
        if (grow < M) {
          if (jb.Cf) {
            *(float4*)(jb.Cf + (size_t)grow * 200 + cw * 4) = v;
          } else {
            ushort4 o = {bf16rne(v.x), bf16rne(v.y), bf16rne(v.z), bf16rne(v.w)};
            *(ushort4*)(jb.Cbf + (size_t)grow * 200 + cw * 4) = o;
          }
        }
      }
    }
  }
}

// ---------------- fused weight conversion (5 jobs) ----------------
__global__ __launch_bounds__(256) void convAll(const float* __restrict__ ah,
                                               const float* __restrict__ W_ent,
                                               const float* __restrict__ a_out,
                                               unsigned short* __restrict__ B1s,
                                               unsigned short* __restrict__ B1d,
                                               unsigned short* __restrict__ Bxw,
                                               unsigned short* __restrict__ B2s,
                                               unsigned short* __restrict__ B2d) {
  int idx = blockIdx.x * 256 + threadIdx.x;
  int y = blockIdx.y;
  if (y < 2) {
    if (idx >= 208 * 128) return;
    int j = idx >> 7, k = idx & 127;
    float v = 0.f;
    if (j < 200 && k < 100)
      v = ah[((j < 100) ? 0 : 30000) + (j % 100) * 300 + (y == 0 ? 0 : 100) + k];
    (y == 0 ? B1s : B1d)[idx] = bf16rne(v);
  } else if (y == 2) {
    if (idx >= 208 * 128) return;
    int j = idx >> 7, k = idx & 127;
    float v = (j < 200 && k < 100) ? W_ent[(size_t)k * 200 + j] : 0.f;
    Bxw[idx] = bf16rne(v);
  } else {
    if (idx >= 208 * 224) return;
    int j = idx / 224, k = idx - j * 224;
    const float* s = (y == 3) ? a_out : a_out + 200;
    float v = (j < 200 && k < 200) ? s[(size_t)j * 600 + k] : 0.f;
    (y == 3 ? B2s : B2d)[idx] = bf16rne(v);
  }
}

// ---------------- f32 GEMM (small, rel matrices) ----------------
__global__ __launch_bounds__(256) void gemm2_f32(const float* __restrict__ A, int M, int Kd, int lda,
                                                 const float* __restrict__ W, int wsj, int wsk,
                                                 float* __restrict__ C, int ldc, int Ncols, int col0) {
  __shared__ float As[16][132];
  __shared__ float Bs[16][68];
  int tid = threadIdx.x;
  int tx = tid & 15, ty = tid >> 4;
  int row0 = blockIdx.y * 128;
  int colb = blockIdx.x * 64;
  float acc[8][4];
  #pragma unroll
  for (int i = 0; i < 8; ++i)
    #pragma unroll
    for (int j = 0; j < 4; ++j) acc[i][j] = 0.f;
  for (int kt = 0; kt < Kd; kt += 16) {
    #pragma unroll
    for (int l = 0; l < 8; ++l) {
      int idx = tid + l * 256;
      int m = idx >> 4, k = idx & 15;
      int gm = row0 + m, gk = kt + k;
      As[k][m] = (gm < M && gk < Kd) ? A[(size_t)gm * lda + gk] : 0.f;
    }
    #pragma unroll
    for (int l = 0; l < 4; ++l) {
      int idx = tid + l * 256;
      int j = idx >> 4, k = idx & 15;
      int gj = colb + j, gk = kt + k;
      Bs[k][j] = (gj < Ncols && gk < Kd) ? W[(size_t)gj * wsj + (size_t)gk * wsk] : 0.f;
    }
    __syncthreads();
    #pragma unroll
    for (int k = 0; k < 16; ++k) {
      float4 bv = *(const float4*)&Bs[k][tx * 4];
      float4 a0 = *(const float4*)&As[k][ty * 8];
      float4 a1 = *(const float4*)&As[k][ty * 8 + 4];
      float av[8] = {a0.x, a0.y, a0.z, a0.w, a1.x, a1.y, a1.z, a1.w};
      float bb[4] = {bv.x, bv.y, bv.z, bv.w};
      #pragma unroll
      for (int i = 0; i < 8; ++i)
        #pragma unroll
        for (int j = 0; j < 4; ++j)
          acc[i][j] += av[i] * bb[j];
    }
    __syncthreads();
  }
  int gj0 = colb + tx * 4;
  #pragma unroll
  for (int i = 0; i < 8; ++i) {
    int gm = row0 + ty * 8 + i;
    if (gm >= M) continue;
    float* cp = C + (size_t)gm * ldc + col0;
    #pragma unroll
    for (int j = 0; j < 4; ++j) if (gj0 + j < Ncols) cp[gj0 + j] = acc[i][j];
  }
}

// ---------------- per-row dots (rel rows only) ----------------
__global__ __launch_bounds__(256) void dot2h(const float* __restrict__ P, const float* __restrict__ a2,
                                             float* __restrict__ outp, int M) {
  int row  = blockIdx.x * 4 + (threadIdx.x >> 6);
  int lane = threadIdx.x & 63;
  if (row >= M) return;
  const float* pr = P + (size_t)row * 200;
  float s0 = 0.f, s1 = 0.f;
  for (int k = lane; k < 100; k += 64) {
    s0 += pr[k] * a2[k];
    s1 += pr[100 + k] * a2[100 + k];
  }
  #pragma unroll
  for (int off = 1; off < 64; off <<= 1) { s0 += __shfl_xor(s0, off); s1 += __shfl_xor(s1, off); }
  if (lane == 0) { outp[row * 2] = s0; outp[row * 2 + 1] = s1; }
}

__global__ __launch_bounds__(256) void dot1(const float* __restrict__ P, const float* __restrict__ a2,
                                            float* __restrict__ outp, int M) {
  int row  = blockIdx.x * 4 + (threadIdx.x >> 6);
  int lane = threadIdx.x & 63;
  if (row >= M) return;
  const float* pr = P + (size_t)row * 200;
  float s = 0.f;
  for (int k = lane; k < 200; k += 64) s += pr[k] * a2[k];
  #pragma unroll
  for (int off = 1; off < 64; off <<= 1) s += __shfl_xor(s, off);
  if (lane == 0) outp[row] = s;
}

// ---------------- relp f32 -> bf16 copy ----------------
__global__ __launch_bounds__(256) void relpconv(const float* __restrict__ src,
                                                unsigned short* __restrict__ dst) {
  int i = blockIdx.x * 256 + threadIdx.x;
  if (i < NRELS * 200) dst[i] = bf16rne(src[i]);
}

// ---------------- CSR build ----------------
__global__ __launch_bounds__(256) void histk(const int* __restrict__ el, const int* __restrict__ tin,
                                             int* __restrict__ deg) {
  int i = blockIdx.x * 256 + threadIdx.x;
  if (i >= ETOT) return;
  int e0 = (i < NEDGE) ? el[i] : tin[(size_t)(i - NEDGE) * 4 + 3];
  atomicAdd(&deg[e0], 1);
}

__global__ __launch_bounds__(256) void scanA(const int* __restrict__ deg, int* __restrict__ bsum, int n) {
  __shared__ int s[256];
  int t = threadIdx.x;
  int i = blockIdx.x * 256 + t;
  s[t] = (i < n) ? deg[i] : 0;
  __syncthreads();
  for (int off = 128; off > 0; off >>= 1) {
    if (t < off) s[t] += s[t + off];
    __syncthreads();
  }
  if (t == 0) bsum[blockIdx.x] = s[0];
}

__global__ __launch_bounds__(256) void scanB(int* __restrict__ bsum, int nb) {
  __shared__ int s[256];
  int t = threadIdx.x;
  int v = (t < nb) ? bsum[t] : 0;
  s[t] = v;
  __syncthreads();
  for (int off = 1; off < 256; off <<= 1) {
    int add = (t >= off) ? s[t - off] : 0;
    __syncthreads();
    s[t] += add;
    __syncthreads();
  }
  if (t < nb) bsum[t] = s[t] - v;  // exclusive
}

__global__ __launch_bounds__(256) void scanC(const int* __restrict__ deg, const int* __restrict__ bsum,
                                             int* __restrict__ offs, int* __restrict__ pos, int n, int total) {
  __shared__ int s[256];
  int t = threadIdx.x;
  int i = blockIdx.x * 256 + t;
  int v = (i < n) ? deg[i] : 0;
  s[t] = v;
  __syncthreads();
  for (int off = 1; off < 256; off <<= 1) {
    int add = (t >= off) ? s[t - off] : 0;
    __syncthreads();
    s[t] += add;
    __syncthreads();
  }
  if (i < n) {
    int e = bsum[blockIdx.x] + s[t] - v;
    offs[i] = e;
    pos[i]  = e;
  }
  if (i == 0) offs[n] = total;
}

// edata: .x = e1 | (t1<<16), .y = t2f | (e0<<9)
__global__ __launch_bounds__(256) void scatterk(const int* __restrict__ el, const int* __restrict__ et,
                                                const int* __restrict__ tin,
                                                int* __restrict__ pos, int2* __restrict__ edata) {
  int i = blockIdx.x * 256 + threadIdx.x;
  if (i >= ETOT) return;
  int e0, e1, t1, t2f;
  if (i < NEDGE) {
    e0 = el[i]; e1 = el[NEDGE + i]; t1 = et[i]; t2f = 0;
  } else {
    const int* q = tin + (size_t)(i - NEDGE) * 4;
    e0 = q[3]; e1 = q[0]; t1 = q[1]; t2f = q[2] + 1;
  }
  int slot = atomicAdd(&pos[e0], 1);
  edata[slot] = make_int2(e1 | (t1 << 16), t2f | (e0 << 9));
}

// wave-aggregated list append
__global__ __launch_bounds__(256) void buildLists(const int* __restrict__ offs,
                                                  int* __restrict__ lightL, int* __restrict__ heavyL,
                                                  int* __restrict__ cnts) {
  int i = blockIdx.x * 256 + threadIdx.x;
  int lane = threadIdx.x & 63;
  bool valid = (i < NN);
  int d = valid ? (offs[i + 1] - offs[i]) : 0;
  bool heavy = valid && (d > 64);
  bool light = valid && (d <= 64);
  unsigned long long mh = __ballot(heavy);
  unsigned long long ml = __ballot(light);
  unsigned long long below = (1ULL << lane) - 1ULL;
  int bh = 0, bl = 0;
  if (lane == 0) {
    if (mh) bh = atomicAdd(&cnts[1], __popcll(mh));
    if (ml) bl = atomicAdd(&cnts[0], __popcll(ml));
  }
  bh = __shfl(bh, 0);
  bl = __shfl(bl, 0);
  if (heavy) heavyL[bh + __popcll(mh & below)] = i;
  if (light) lightL[bl + __popcll(ml & below)] = i;
}

// ---------------- per-edge attention precompute ----------------
__global__ __launch_bounds__(256) void edgeEE1(const int2* __restrict__ edata,
                                               const float* __restrict__ ssrc,
                                               const float* __restrict__ sdst,
                                               const float* __restrict__ srel,
                                               float2* __restrict__ ee) {
  int q = blockIdx.x * 256 + threadIdx.x;
  if (q >= ETOT) return;
  int2 ed = edata[q];
  int e1 = ed.x & 0xFFFF;
  int t1 = ((unsigned)ed.x) >> 16;
  int t2f = ed.y & 0x1FF;
  int e0 = ((unsigned)ed.y) >> 9;
  float p0 = ssrc[e0 * 2]     + sdst[e1 * 2]     + srel[t1 * 2];
  float p1 = ssrc[e0 * 2 + 1] + sdst[e1 * 2 + 1] + srel[t1 * 2 + 1];
  if (t2f) { int t2 = t2f - 1; p0 += srel[t2 * 2]; p1 += srel[t2 * 2 + 1]; }
  p0 = (p0 > 0.f) ? p0 : 0.2f * p0;
  p1 = (p1 > 0.f) ? p1 : 0.2f * p1;
  ee[q] = make_float2(__expf(-p0), __expf(-p1));
}

__global__ __launch_bounds__(256) void edgeEE2(const int2* __restrict__ edata,
                                               const float* __restrict__ ssrc,
                                               const float* __restrict__ sdst,
                                               const float* __restrict__ srel,
                                               float* __restrict__ ee) {
  int q = blockIdx.x * 256 + threadIdx.x;
  if (q >= ETOT) return;
  int2 ed = edata[q];
  int e1 = ed.x & 0xFFFF;
  int t1 = ((unsigned)ed.x) >> 16;
  int t2f = ed.y & 0x1FF;
  int e0 = ((unsigned)ed.y) >> 9;
  float p = ssrc[e0] + sdst[e1] + srel[t1];
  if (t2f) p += srel[t2f - 1];
  p = (p > 0.f) ? p : 0.2f * p;
  ee[q] = __expf(-p);
}

// ---------------- merged layer-1 gather (heavy-first), ee-precomputed, all-bf16 operands ----------------
__global__ __launch_bounds__(512) void gather1M(const int* __restrict__ lightL, const int* __restrict__ heavyL,
    const int* __restrict__ cnts, const int* __restrict__ offs, const int2* __restrict__ edata,
    const float2* __restrict__ eeb,
    const unsigned short* __restrict__ srcb, const unsigned short* __restrict__ dstb,
    const unsigned short* __restrict__ relpb,
    unsigned short* __restrict__ xbf) {
  __shared__ float part[8][208];
  int w = threadIdx.x >> 6, lane = threadIdx.x & 63;
  bool act = lane < 50;
  int cb = lane * 4;
  float a0 = 0.f, a1 = 0.f, a2v = 0.f, a3 = 0.f, rs0 = 0.f, rs1 = 0.f;
  bool hd0 = (cb < 100);
  auto edgeop = [&](int2 ed, float2 ev) {
    int e1 = ed.x & 0xFFFF;
    int t1 = ((unsigned)ed.x) >> 16;
    int t2f = ed.y & 0x1FF;
    rs0 += ev.x; rs1 += ev.y;
    if (act) {
      ushort4 dv = *(const ushort4*)(dstb + (size_t)e1 * 200 + cb);
      ushort4 rv = *(const ushort4*)(relpb + (size_t)t1 * 200 + cb);
      float m0 = b2f(dv.x) + b2f(rv.x);
      float m1 = b2f(dv.y) + b2f(rv.y);
      float m2 = b2f(dv.z) + b2f(rv.z);
      float m3 = b2f(dv.w) + b2f(rv.w);
      if (t2f) {
        ushort4 r2 = *(const ushort4*)(relpb + (size_t)(t2f - 1) * 200 + cb);
        m0 += b2f(r2.x); m1 += b2f(r2.y); m2 += b2f(r2.z); m3 += b2f(r2.w);
      }
      float ee = hd0 ? ev.x : ev.y;
      a0 += ee * m0; a1 += ee * m1; a2v += ee * m2; a3 += ee * m3;
    }
  };
  if (blockIdx.x < HBMAX) {
    int hidx = blockIdx.x;
    if (hidx >= cnts[1]) return;
    int node = heavyL[hidx];
    int s = offs[node], e = offs[node + 1];
    int q = s + w;
    for (; q + 8 < e; q += 16) { edgeop(edata[q], eeb[q]); edgeop(edata[q + 8], eeb[q + 8]); }
    if (q < e) edgeop(edata[q], eeb[q]);
    if (act) { part[w][cb] = a0; part[w][cb + 1] = a1; part[w][cb + 2] = a2v; part[w][cb + 3] = a3; }
    if (lane == 0) { part[w][200] = rs0; part[w][201] = rs1; }
    __syncthreads();
    int t = threadIdx.x;
    if (t < 224) {
      unsigned short outv = 0;
      if (t < 200) {
        float a = 0.f, r0 = 0.f, r1 = 0.f;
        #pragma unroll
        for (int wv = 0; wv < 8; ++wv) { a += part[wv][t]; r0 += part[wv][200]; r1 += part[wv][201]; }
        float inv = (t < 100) ? 1.f / r0 : 1.f / r1;
        float v = b2f(srcb[(size_t)node * 200 + t]) + a * inv;
        v = (v > 0.f) ? v : expm1f(v);
        outv = bf16rne(v);
      }
      xbf[(size_t)node * 224 + t] = outv;
    }
    return;
  }
  int widx = (blockIdx.x - HBMAX) * 8 + w;
  if (widx >= cnts[0]) return;
  int node = lightL[widx];
  int s = offs[node], e = offs[node + 1];
  int q = s;
  for (; q + 1 < e; q += 2) { edgeop(edata[q], eeb[q]); edgeop(edata[q + 1], eeb[q + 1]); }
  if (q < e) edgeop(edata[q], eeb[q]);
  bool has = (e > s);
  unsigned short* xo = xbf + (size_t)node * 224;
  if (act) {
    float inv = has ? (hd0 ? 1.f / rs0 : 1.f / rs1) : 0.f;
    ushort4 sv = *(const ushort4*)(srcb + (size_t)node * 200 + cb);
    float v0 = has ? b2f(sv.x) + a0 * inv : 0.f;
    float v1 = has ? b2f(sv.y) + a1 * inv : 0.f;
    float v2 = has ? b2f(sv.z) + a2v * inv : 0.f;
    float v3 = has ? b2f(sv.w) + a3 * inv : 0.f;
    v0 = (v0 > 0.f) ? v0 : expm1f(v0);
    v1 = (v1 > 0.f) ? v1 : expm1f(v1);
    v2 = (v2 > 0.f) ? v2 : expm1f(v2);
    v3 = (v3 > 0.f) ? v3 : expm1f(v3);
    ushort4 ov = {bf16rne(v0), bf16rne(v1), bf16rne(v2), bf16rne(v3)};
    *(ushort4*)(xo + cb) = ov;
  } else if (lane < 56) {
    ushort4 z = {0, 0, 0, 0};
    *(ushort4*)(xo + cb) = z;
  }
}

// ---------------- merged layer-2 gather (heavy-first), ee-precomputed, bf16 out ----------------
__global__ __launch_bounds__(512) void gather2M(const int* __restrict__ lightL, const int* __restrict__ heavyL,
    const int* __restrict__ cnts, const int* __restrict__ offs, const int2* __restrict__ edata,
    const float* __restrict__ eeb,
    const unsigned short* __restrict__ srcb, const unsigned short* __restrict__ dstb,
    const unsigned short* __restrict__ relpb,
    unsigned short* __restrict__ h2b) {
  __shared__ float part[8][208];
  int w = threadIdx.x >> 6, lane = threadIdx.x & 63;
  bool act = lane < 50;
  int cb = lane * 4;
  float a0 = 0.f, a1 = 0.f, a2v = 0.f, a3 = 0.f, rs = 0.f;
  auto edgeop = [&](int2 ed, float ee) {
    int e1 = ed.x & 0xFFFF;
    int t1 = ((unsigned)ed.x) >> 16;
    int t2f = ed.y & 0x1FF;
    rs += ee;
    if (act) {
      ushort4 dv = *(const ushort4*)(dstb + (size_t)e1 * 200 + cb);
      ushort4 rv = *(const ushort4*)(relpb + (size_t)t1 * 200 + cb);
      float m0 = b2f(dv.x) + b2f(rv.x);
      float m1 = b2f(dv.y) + b2f(rv.y);
      float m2 = b2f(dv.z) + b2f(rv.z);
      float m3 = b2f(dv.w) + b2f(rv.w);
      if (t2f) {
        ushort4 r2 = *(const ushort4*)(relpb + (size_t)(t2f - 1) * 200 + cb);
        m0 += b2f(r2.x); m1 += b2f(r2.y); m2 += b2f(r2.z); m3 += b2f(r2.w);
      }
      a0 += ee * m0; a1 += ee * m1; a2v += ee * m2; a3 += ee * m3;
    }
  };
  if (blockIdx.x < HBMAX) {
    int hidx = blockIdx.x;
    if (hidx >= cnts[1]) return;
    int node = heavyL[hidx];
    int s = offs[node], e = offs[node + 1];
    int q = s + w;
    for (; q + 8 < e; q += 16) { edgeop(edata[q], eeb[q]); edgeop(edata[q + 8], eeb[q + 8]); }
    if (q < e) edgeop(edata[q], eeb[q]);
    if (act) { part[w][cb] = a0; part[w][cb + 1] = a1; part[w][cb + 2] = a2v; part[w][cb + 3] = a3; }
    if (lane == 0) part[w][200] = rs;
    __syncthreads();
    int t = threadIdx.x;
    if (t < 200) {
      float a = 0.f, r = 0.f;
      #pragma unroll
      for (int wv = 0; wv < 8; ++wv) { a += part[wv][t]; r += part[wv][200]; }
      float v = b2f(srcb[(size_t)node * 200 + t]) + a / r;
      v = (v > 0.f) ? v : expm1f(v);
      h2b[(size_t)node * 200 + t] = bf16rne(v);
    }
    return;
  }
  int widx = (blockIdx.x - HBMAX) * 8 + w;
  if (widx >= cnts[0]) return;
  int node = lightL[widx];
  int s = offs[node], e = offs[node + 1];
  int q = s;
  for (; q + 1 < e; q += 2) { edgeop(edata[q], eeb[q]); edgeop(edata[q + 1], eeb[q + 1]); }
  if (q < e) edgeop(edata[q], eeb[q]);
  if (!act) return;
  bool has = (e > s);
  float inv = has ? 1.f / rs : 0.f;
  ushort4 sv = *(const ushort4*)(srcb + (size_t)node * 200 + cb);
  float v0 = has ? b2f(sv.x) + a0 * inv : 0.f;
  float v1 = has ? b2f(sv.y) + a1 * inv : 0.f;
  float v2 = has ? b2f(sv.z) + a2v * inv : 0.f;
  float v3 = has ? b2f(sv.w) + a3 * inv : 0.f;
  v0 = (v0 > 0.f) ? v0 : expm1f(v0);
  v1 = (v1 > 0.f) ? v1 : expm1f(v1);
  v2 = (v2 > 0.f) ? v2 : expm1f(v2);
  v3 = (v3 > 0.f) ? v3 : expm1f(v3);
  ushort4 ov = {bf16rne(v0), bf16rne(v1), bf16rne(v2), bf16rne(v3)};
  *(ushort4*)(h2b + (size_t)node * 200 + cb) = ov;
}

// ---------------- pad xbf rows [NN, MP) ----------------
__global__ __launch_bounds__(256) void padx(unsigned short* __restrict__ xbf) {
  int i = blockIdx.x * 256 + threadIdx.x;
  if (i < (MP - NN) * 224) xbf[(size_t)NN * 224 + i] = 0;
}

// ---------------- mask scatter ----------------
__global__ __launch_bounds__(256) void maskset(const int* __restrict__ bi, float* __restrict__ maskA) {
  int t = blockIdx.x * 256 + threadIdx.x;
  if (t < BATCH) maskA[bi[t * 3 + 2]] = 1.0f;
}

// ---------------- final: out = l2norm(xw + mask*h2), blocked lanes ----------------
__global__ __launch_bounds__(256) void finalk2(const float* __restrict__ xw,
                                               const unsigned short* __restrict__ h2b,
                                               const float* __restrict__ maskA, float* __restrict__ out) {
  int row  = blockIdx.x * 4 + (threadIdx.x >> 6);
  int lane = threadIdx.x & 63;
  if (row >= NN) return;
  bool act = lane < 50;
  int cb = lane * 4;
  float m = maskA[row];
  float v0 = 0.f, v1 = 0.f, v2 = 0.f, v3 = 0.f;
  if (act) {
    float4 xv = *(const float4*)(xw + (size_t)row * 200 + cb);
    ushort4 hv = *(const ushort4*)(h2b + (size_t)row * 200 + cb);
    v0 = xv.x + m * b2f(hv.x);
    v1 = xv.y + m * b2f(hv.y);
    v2 = xv.z + m * b2f(hv.z);
    v3 = xv.w + m * b2f(hv.w);
  }
  float ss = v0 * v0 + v1 * v1 + v2 * v2 + v3 * v3;
  #pragma unroll
  for (int off = 1; off < 64; off <<= 1) ss += __shfl_xor(ss, off);
  float inv = 1.f / fmaxf(sqrtf(ss), 1e-12f);
  if (act) {
    float4 ov = {v0 * inv, v1 * inv, v2 * inv, v3 * inv};
    *(float4*)(out + (size_t)row * 200 + cb) = ov;
  }
}

extern "C" void kernel_launch(void* const* d_in, const int* in_sizes, int n_in,
                              void* d_out, int out_size, void* d_ws, size_t ws_size,
                              hipStream_t stream) {
  (void)in_sizes; (void)n_in; (void)out_size; (void)ws_size;
  const float* ent      = (const float*)d_in[0];
  const float* rel      = (const float*)d_in[1];
  const float* a_heads  = (const float*)d_in[3];
  const float* a2_heads = (const float*)d_in[4];
  const float* W_gat    = (const float*)d_in[5];
  const float* a_out    = (const float*)d_in[6];
  const float* a2_out   = (const float*)d_in[7];
  const float* W_ent    = (const float*)d_in[8];
  const int* edge_list  = (const int*)d_in[9];
  const int* edge_type  = (const int*)d_in[10];
  const int* tin        = (const int*)d_in[11];
  const int* binp       = (const int*)d_in[12];

  float* out    = (float*)d_out;
  float* outrel = out + 10000000;     // (500,200)

  float* ws = (float*)d_ws;
  unsigned short* bufSb = (unsigned short*)ws;                 // NN*200 bf16: srcp1 -> srcp2
  unsigned short* dstD  = (unsigned short*)(ws + 5000000);     // NN*200 bf16: dstp1 -> dstp2
  float* relp1 = ws + 10000000;       // 100k f32
  float* relp2 = ws + 10100000;       // 100k f32
  unsigned short* relp1b = (unsigned short*)(ws + 10200000);   // 100k bf16
  unsigned short* relp2b = (unsigned short*)(ws + 10250000);
  float* ssrc1 = ws + 10300000;       // N*2
  float* sdst1 = ws + 10400000;       // N*2
  float* s2src = ws + 10500000;       // N
  float* s2dst = ws + 10550000;       // N
  float* srel1 = ws + 10600000;       // 1000
  float* s2rel = ws + 10601000;       // 500
  float* maskA = ws + 10602000;       // N
  unsigned short* h2b   = (unsigned short*)(ws + 10660000);    // NN*200 bf16
  unsigned short* x0nbf = (unsigned short*)(ws + 15700000);    // MP*128 bf16
  unsigned short* xbf   = (unsigned short*)(ws + 18950000);    // MP*224 bf16
  unsigned short* B1s   = (unsigned short*)(ws + 24600000);    // 208*128
  unsigned short* B1d   = (unsigned short*)(ws + 24620000);
  unsigned short* Bxw   = (unsigned short*)(ws + 24640000);
  unsigned short* B2s   = (unsigned short*)(ws + 24660000);    // 208*224
  unsigned short* B2d   = (unsigned short*)(ws + 24690000);
  float2* eeb1 = (float2*)(ws + 24720000);   // ETOT float2
  float*  eeb2 = ws + 25470000;              // ETOT float
  int* ibase  = (int*)(ws + 25850000);
  int* deg    = ibase;                // 50k
  int* offs   = ibase + 50000;        // 50k+1
  int* pos    = ibase + 100016;       // 50k
  int* bsum   = ibase + 150016;       // 256
  int* cnts   = ibase + 150272;       // 2 (+pad)
  int* lightL = ibase + 150280;       // 50k
  int* heavyL = ibase + 200280;       // 50k (+pad)
  int2* edata = (int2*)(ibase + 250288); // 375k int2

  hipMemsetAsync(deg,   0, (size_t)NN * 4, stream);
  hipMemsetAsync(maskA, 0, (size_t)NN * 4, stream);
  hipMemsetAsync(cnts,  0, 8, stream);

  l2norm_bf16<<<12512, 256, 0, stream>>>(ent, x0nbf);

  // CSR + lists
  histk<<<(ETOT + 255) / 256, 256, 0, stream>>>(edge_list, tin, deg);
  scanA<<<196, 256, 0, stream>>>(deg, bsum, NN);
  scanB<<<1, 256, 0, stream>>>(bsum, 196);
  scanC<<<196, 256, 0, stream>>>(deg, bsum, offs, pos, NN, ETOT);
  scatterk<<<(ETOT + 255) / 256, 256, 0, stream>>>(edge_list, edge_type, tin, pos, edata);
  buildLists<<<196, 256, 0, stream>>>(offs, lightL, heavyL, cnts);

  // weight conversion (fused, 5 jobs)
  {
    dim3 g(182, 5);
    convAll<<<g, 256, 0, stream>>>(a_heads, W_ent, a_out, B1s, B1d, Bxw, B2s, B2d);
  }

  // layer-1 projections + xw, one 3-job launch (srcp/dstp -> bf16, dots fused)
  {
    GJob js = {B1s, nullptr, bufSb, a2_heads, ssrc1, 1};
    GJob jd = {B1d, nullptr, dstD, a2_heads, sdst1, 1};
    GJob jx = {Bxw, out, nullptr, nullptr, nullptr, 0};
    dim3 g(782, 3);
    gemm_multi<128><<<g, 256, 0, stream>>>(x0nbf, js, jd, jx, NN);
  }

  // rel projections (f32) + rel dots + bf16 copy
  dim3 g2(2, 4);
  gemm2_f32<<<g2, 256, 0, stream>>>(rel, NRELS, 100, 100, a_heads + 200,         300, 1, relp1, 200, 100, 0);
  gemm2_f32<<<g2, 256, 0, stream>>>(rel, NRELS, 100, 100, a_heads + 30000 + 200, 300, 1, relp1, 200, 100, 100);
  dot2h<<<125, 256, 0, stream>>>(relp1, a2_heads, srel1, NRELS);
  relpconv<<<391, 256, 0, stream>>>(relp1, relp1b);

  edgeEE1<<<(ETOT + 255) / 256, 256, 0, stream>>>(edata, ssrc1, sdst1, srel1, eeb1);

  gather1M<<<HBMAX + LB1, 512, 0, stream>>>(lightL, heavyL, cnts, offs, edata, eeb1,
                                            bufSb, dstD, relp1b, xbf);
  padx<<<42, 256, 0, stream>>>(xbf);

  // layer-2 projections, one 2-job launch (overwrites bufSb/dstD)
  {
    GJob js = {B2s, nullptr, bufSb, a2_out, s2src, 2};
    GJob jd = {B2d, nullptr, dstD, a2_out, s2dst, 2};
    GJob jz = {B2s, nullptr, nullptr, nullptr, nullptr, 0};
    dim3 g(782, 2);
    gemm_multi<224><<<g, 256, 0, stream>>>(xbf, js, jd, jz, NN);
  }

  // out_relation_1, relp2, rel dot, bf16 copy
  dim3 g3(4, 4);
  gemm2_f32<<<g3, 256, 0, stream>>>(rel, NRELS, 100, 100, W_gat, 1, 200, outrel, 200, 200, 0);
  gemm2_f32<<<g3, 256, 0, stream>>>(outrel, NRELS, 200, 200, a_out + 400, 600, 1, relp2, 200, 200, 0);
  dot1<<<125, 256, 0, stream>>>(relp2, a2_out, s2rel, NRELS);
  relpconv<<<391, 256, 0, stream>>>(relp2, relp2b);

  edgeEE2<<<(ETOT + 255) / 256, 256, 0, stream>>>(edata, s2src, s2dst, s2rel, eeb2);

  maskset<<<256, 256, 0, stream>>>(binp, maskA);

  gather2M<<<HBMAX + LB1, 512, 0, stream>>>(lightL, heavyL, cnts, offs, edata, eeb2,
                                            bufSb, dstD, relp2b, h2b);

  finalk2<<<12500, 256, 0, stream>>>(out, h2b, maskA, out);
}

// Round 12
// 390.229 us; speedup vs baseline: 1.5794x; 1.3922x over previous
//
#include <hip/hip_runtime.h>
#include <math.h>

#define NN    50000
#define MP    50048    // padded rows (782*64)
#define NEDGE 250000
#define NHOPE 125000
#define ETOT  375000
#define NRELS 500
#define BATCH 65536
#define LB1   6250     // light blocks (8 waves each -> 50000 waves)
#define HBMAX 5769     // max heavy nodes (deg>64): 375000/65

typedef __attribute__((ext_vector_type(8))) short bf16x8;
typedef __attribute__((ext_vector_type(4))) float f32x4;

__device__ __forceinline__ unsigned short bf16rne(float f) {
  unsigned u = __float_as_uint(f);
  unsigned r = (u + 0x7FFFu + ((u >> 16) & 1u)) >> 16;
  return (unsigned short)r;
}
__device__ __forceinline__ float b2f(unsigned short u) {
  return __uint_as_float(((unsigned)u) << 16);
}

struct GJob {
  const unsigned short* A;   // (>=ceil(M/64)*64) x KP bf16, zero-padded
  int M;                     // valid rows
  const unsigned short* B;   // 208 x KP bf16
  float* Cf;                 // f32 out (ld 200) or null
  unsigned short* Cbf;       // bf16 out (ld ldcb) or null
  int ldcb;
  const float* a2;           // 200 floats or null
  float* dot;                // per-row scalar(s) or null
  int dotmode;               // 1 = split at 100 (two heads), 2 = single sum
};

// ---------------- fused: l2norm (y=0) + histk (y=1) ----------------
__global__ __launch_bounds__(256) void startk(const float* __restrict__ in,
                                              unsigned short* __restrict__ out,
                                              const int* __restrict__ el, const int* __restrict__ tin,
                                              int* __restrict__ deg) {
  if (blockIdx.y == 1) {
    int i = blockIdx.x * 256 + threadIdx.x;
    if (i < ETOT) {
      int e0 = (i < NEDGE) ? el[i] : tin[(size_t)(i - NEDGE) * 4 + 3];
      atomicAdd(&deg[e0], 1);
    }
    return;
  }
  int row  = blockIdx.x * 4 + (threadIdx.x >> 6);
  int lane = threadIdx.x & 63;
  if (row >= MP) return;
  unsigned short* o = out + (size_t)row * 128;
  if (row >= NN) { o[lane] = 0; o[lane + 64] = 0; return; }
  const float* r = in + (size_t)row * 100;
  float v0 = r[lane];
  float v1 = (lane + 64 < 100) ? r[lane + 64] : 0.f;
  float ss = v0 * v0 + v1 * v1;
  #pragma unroll
  for (int off = 1; off < 64; off <<= 1) ss += __shfl_xor(ss, off);
  float inv = 1.f / fmaxf(sqrtf(ss), 1e-12f);
  o[lane] = bf16rne(v0 * inv);
  o[lane + 64] = (lane + 64 < 100) ? bf16rne(v1 * inv) : (unsigned short)0;
}

// ---------------- multi-job bf16 MFMA GEMM, LDS-staged B, LDS-coalesced epilogue ----------------
template<int KP>
__global__ __launch_bounds__(256) void gemm_multi(GJob j0, GJob j1, GJob j2, GJob j3, GJob j4) {
  __shared__ __attribute__((aligned(16))) char smem[54272];
  unsigned short* shb = (unsigned short*)smem;
  float (*clds)[16][212] = (float (*)[16][212])smem;   // [4][16][212]
  GJob jb = (blockIdx.y == 0) ? j0 : (blockIdx.y == 1) ? j1 : (blockIdx.y == 2) ? j2
          : (blockIdx.y == 3) ? j3 : j4;
  if (blockIdx.x * 64 >= jb.M) return;   // block-uniform early exit
  int wv = threadIdx.x >> 6, lane = threadIdx.x & 63;
  int rbw = blockIdx.x * 64 + wv * 16;
  int rl = lane & 15;
  int kq = (lane >> 4) * 8;
  const unsigned short* ap = jb.A + (size_t)(rbw + rl) * KP + kq;
  f32x4 acc[13];
  #pragma unroll
  for (int t = 0; t < 13; ++t) acc[t] = (f32x4){0.f, 0.f, 0.f, 0.f};
  constexpr int NST = (KP + 63) / 64;
  #pragma unroll
  for (int s = 0; s < NST; ++s) {
    const int ks0 = s * 64;
    const int sw  = (KP - ks0 >= 64) ? 64 : (KP - ks0);
    const int cpr = sw / 8;
    __syncthreads();
    for (int idx = threadIdx.x; idx < 208 * cpr; idx += 256) {
      int row = idx / cpr, cw = idx - row * cpr;
      *(float4*)(shb + row * 72 + cw * 8) =
          *(const float4*)(jb.B + (size_t)row * KP + ks0 + cw * 8);
    }
    __syncthreads();
    for (int ksl = 0; ksl < sw; ksl += 32) {
      bf16x8 a0 = *(const bf16x8*)(ap + ks0 + ksl);
      const unsigned short* bl = shb + (size_t)rl * 72 + kq + ksl;
      #pragma unroll
      for (int t = 0; t < 13; ++t) {
        bf16x8 b = *(const bf16x8*)(bl + t * 16 * 72);
        acc[t] = __builtin_amdgcn_mfma_f32_16x16x32_bf16(a0, b, acc[t], 0, 0, 0);
      }
    }
  }
  int rg = (lane >> 4) * 4;
  if (jb.dot) {
    float p0[4] = {0.f, 0.f, 0.f, 0.f}, p1[4] = {0.f, 0.f, 0.f, 0.f};
    #pragma unroll
    for (int t = 0; t < 13; ++t) {
      int col = t * 16 + rl;
      float av = (col < 200) ? jb.a2[col] : 0.f;
      bool lo = (col < 100);
      #pragma unroll
      for (int g = 0; g < 4; ++g) {
        float v = acc[t][g] * av;
        if (lo) p0[g] += v; else p1[g] += v;
      }
    }
    #pragma unroll
    for (int off = 1; off < 16; off <<= 1) {
      #pragma unroll
      for (int g = 0; g < 4; ++g) {
        p0[g] += __shfl_xor(p0[g], off);
        p1[g] += __shfl_xor(p1[g], off);
      }
    }
    if (rl == 0) {
      #pragma unroll
      for (int g = 0; g < 4; ++g) {
        int row = rbw + rg + g;
        if (row < jb.M) {
          if (jb.dotmode == 1) { jb.dot[row * 2] = p0[g]; jb.dot[row * 2 + 1] = p1[g]; }
          else                 { jb.dot[row] = p0[g] + p1[g]; }
        }
      }
    }
  }
  if (jb.Cf || jb.Cbf) {
    __syncthreads();
    #pragma unroll
    for (int t = 0; t < 13; ++t) {
      #pragma unroll
      for (int g = 0; g < 4; ++g)
        clds[wv][rg + g][t * 16 + rl] = acc[t][g];
    }
    __syncthreads();
    #pragma unroll
    for (int i = 0; i < 13; ++i) {
      int idx = i * 64 + lane;
      if (idx < 800) {
        int r = idx / 50, cw = idx - r * 50;
        float4 v = *(const float4*)&clds[wv][r][cw * 4];
        int grow = rbw + r;
        if (grow < jb.M) {
          if (jb.Cf)
            *(float4*)(jb.Cf + (size_t)grow * 200 + cw * 4) = v;
          if (jb.Cbf) {
            ushort4 o = {bf16rne(v.x), bf16rne(v.y), bf16rne(v.z), bf16rne(v.w)};
            *(ushort4*)(jb.Cbf + (size_t)grow * jb.ldcb + cw * 4) = o;
          }
        }
      }
    }
  }
}

// ---------------- fused weight/operand conversion (9 jobs) ----------------
__global__ __launch_bounds__(256) void convAll(const float* __restrict__ rel,
                                               const float* __restrict__ ah,
                                               const float* __restrict__ W_ent,
                                               const float* __restrict__ W_gat,
                                               const float* __restrict__ a_out,
                                               unsigned short* __restrict__ B1s,
                                               unsigned short* __restrict__ B1d,
                                               unsigned short* __restrict__ Brel1,
                                               unsigned short* __restrict__ Bxw,
                                               unsigned short* __restrict__ Bwgat,
                                               unsigned short* __restrict__ B2s,
                                               unsigned short* __restrict__ B2d,
                                               unsigned short* __restrict__ B2rel,
                                               unsigned short* __restrict__ relbf) {
  int idx = blockIdx.x * 256 + threadIdx.x;
  int y = blockIdx.y;
  if (y < 3) {                       // B1s / B1d / Brel1 : 208x128 from a_heads slice
    if (idx >= 208 * 128) return;
    int j = idx >> 7, k = idx & 127;
    float v = 0.f;
    if (j < 200 && k < 100)
      v = ah[((j < 100) ? 0 : 30000) + (j % 100) * 300 + y * 100 + k];
    (y == 0 ? B1s : (y == 1 ? B1d : Brel1))[idx] = bf16rne(v);
  } else if (y == 3) {               // Bxw : W_ent^T
    if (idx >= 208 * 128) return;
    int j = idx >> 7, k = idx & 127;
    float v = (j < 200 && k < 100) ? W_ent[(size_t)k * 200 + j] : 0.f;
    Bxw[idx] = bf16rne(v);
  } else if (y == 4) {               // Bwgat : W_gat^T (100,200)->208x128
    if (idx >= 208 * 128) return;
    int j = idx >> 7, k = idx & 127;
    float v = (j < 200 && k < 100) ? W_gat[(size_t)k * 200 + j] : 0.f;
    Bwgat[idx] = bf16rne(v);
  } else if (y < 8) {                // B2s / B2d / B2rel : 208x224 from a_out slices
    if (idx >= 208 * 224) return;
    int j = idx / 224, k = idx - j * 224;
    int off = (y - 5) * 200;
    float v = (j < 200 && k < 200) ? a_out[(size_t)j * 600 + off + k] : 0.f;
    (y == 5 ? B2s : (y == 6 ? B2d : B2rel))[idx] = bf16rne(v);
  } else {                           // relbf : 512x128 from rel (500,100)
    if (idx >= 512 * 128) return;
    int j = idx >> 7, k = idx & 127;
    float v = (j < 500 && k < 100) ? rel[(size_t)j * 100 + k] : 0.f;
    relbf[idx] = bf16rne(v);
  }
}

// ---------------- CSR scans ----------------
__global__ __launch_bounds__(256) void scanA(const int* __restrict__ deg, int* __restrict__ bsum, int n) {
  __shared__ int s[256];
  int t = threadIdx.x;
  int i = blockIdx.x * 256 + t;
  s[t] = (i < n) ? deg[i] : 0;
  __syncthreads();
  for (int off = 128; off > 0; off >>= 1) {
    if (t < off) s[t] += s[t + off];
    __syncthreads();
  }
  if (t == 0) bsum[blockIdx.x] = s[0];
}

__global__ __launch_bounds__(256) void scanB(int* __restrict__ bsum, int nb) {
  __shared__ int s[256];
  int t = threadIdx.x;
  int v = (t < nb) ? bsum[t] : 0;
  s[t] = v;
  __syncthreads();
  for (int off = 1; off < 256; off <<= 1) {
    int add = (t >= off) ? s[t - off] : 0;
    __syncthreads();
    s[t] += add;
    __syncthreads();
  }
  if (t < nb) bsum[t] = s[t] - v;  // exclusive
}

__global__ __launch_bounds__(256) void scanC(const int* __restrict__ deg, const int* __restrict__ bsum,
                                             int* __restrict__ offs, int* __restrict__ pos, int n, int total) {
  __shared__ int s[256];
  int t = threadIdx.x;
  int i = blockIdx.x * 256 + t;
  int v = (i < n) ? deg[i] : 0;
  s[t] = v;
  __syncthreads();
  for (int off = 1; off < 256; off <<= 1) {
    int add = (t >= off) ? s[t - off] : 0;
    __syncthreads();
    s[t] += add;
    __syncthreads();
  }
  if (i < n) {
    int e = bsum[blockIdx.x] + s[t] - v;
    offs[i] = e;
    pos[i]  = e;
  }
  if (i == 0) offs[n] = total;
}

// fused: scatterk (y=0) + buildLists (y=1). edata: .x = e1|(t1<<16), .y = t2f|(e0<<9)
__global__ __launch_bounds__(256) void scatBuild(const int* __restrict__ el, const int* __restrict__ et,
                                                 const int* __restrict__ tin, const int* __restrict__ offs,
                                                 int* __restrict__ pos, int2* __restrict__ edata,
                                                 int* __restrict__ lightL, int* __restrict__ heavyL,
                                                 int* __restrict__ cnts) {
  if (blockIdx.y == 0) {
    int i = blockIdx.x * 256 + threadIdx.x;
    if (i >= ETOT) return;
    int e0, e1, t1, t2f;
    if (i < NEDGE) {
      e0 = el[i]; e1 = el[NEDGE + i]; t1 = et[i]; t2f = 0;
    } else {
      const int* q = tin + (size_t)(i - NEDGE) * 4;
      e0 = q[3]; e1 = q[0]; t1 = q[1]; t2f = q[2] + 1;
    }
    int slot = atomicAdd(&pos[e0], 1);
    edata[slot] = make_int2(e1 | (t1 << 16), t2f | (e0 << 9));
    return;
  }
  int i = blockIdx.x * 256 + threadIdx.x;
  int lane = threadIdx.x & 63;
  bool valid = (i < NN);
  int d = valid ? (offs[i + 1] - offs[i]) : 0;
  bool heavy = valid && (d > 64);
  bool light = valid && (d <= 64);
  unsigned long long mh = __ballot(heavy);
  unsigned long long ml = __ballot(light);
  unsigned long long below = (1ULL << lane) - 1ULL;
  int bh = 0, bl = 0;
  if (lane == 0) {
    if (mh) bh = atomicAdd(&cnts[1], __popcll(mh));
    if (ml) bl = atomicAdd(&cnts[0], __popcll(ml));
  }
  bh = __shfl(bh, 0);
  bl = __shfl(bl, 0);
  if (heavy) heavyL[bh + __popcll(mh & below)] = i;
  if (light) lightL[bl + __popcll(ml & below)] = i;
}

// ---------------- fused: edgeEE1 (y=0) + padx/maskset (y=1) ----------------
__global__ __launch_bounds__(256) void eeMisc1(const int2* __restrict__ edata,
                                               const float* __restrict__ ssrc,
                                               const float* __restrict__ sdst,
                                               const float* __restrict__ srel,
                                               float2* __restrict__ ee,
                                               unsigned short* __restrict__ xbf,
                                               const int* __restrict__ bi,
                                               float* __restrict__ maskA) {
  if (blockIdx.y == 1) {
    if (blockIdx.x < 42) {
      int i = blockIdx.x * 256 + threadIdx.x;
      if (i < (MP - NN) * 224) xbf[(size_t)NN * 224 + i] = 0;
    } else if (blockIdx.x < 42 + 256) {
      int t = (blockIdx.x - 42) * 256 + threadIdx.x;
      if (t < BATCH) maskA[bi[t * 3 + 2]] = 1.0f;
    }
    return;
  }
  int q = blockIdx.x * 256 + threadIdx.x;
  if (q >= ETOT) return;
  int2 ed = edata[q];
  int e1 = ed.x & 0xFFFF;
  int t1 = ((unsigned)ed.x) >> 16;
  int t2f = ed.y & 0x1FF;
  int e0 = ((unsigned)ed.y) >> 9;
  float p0 = ssrc[e0 * 2]     + sdst[e1 * 2]     + srel[t1 * 2];
  float p1 = ssrc[e0 * 2 + 1] + sdst[e1 * 2 + 1] + srel[t1 * 2 + 1];
  if (t2f) { int t2 = t2f - 1; p0 += srel[t2 * 2]; p1 += srel[t2 * 2 + 1]; }
  p0 = (p0 > 0.f) ? p0 : 0.2f * p0;
  p1 = (p1 > 0.f) ? p1 : 0.2f * p1;
  ee[q] = make_float2(__expf(-p0), __expf(-p1));
}

__global__ __launch_bounds__(256) void edgeEE2(const int2* __restrict__ edata,
                                               const float* __restrict__ ssrc,
                                               const float* __restrict__ sdst,
                                               const float* __restrict__ srel,
                                               float* __restrict__ ee) {
  int q = blockIdx.x * 256 + threadIdx.x;
  if (q >= ETOT) return;
  int2 ed = edata[q];
  int e1 = ed.x & 0xFFFF;
  int t1 = ((unsigned)ed.x) >> 16;
  int t2f = ed.y & 0x1FF;
  int e0 = ((unsigned)ed.y) >> 9;
  float p = ssrc[e0] + sdst[e1] + srel[t1];
  if (t2f) p += srel[t2f - 1];
  p = (p > 0.f) ? p : 0.2f * p;
  ee[q] = __expf(-p);
}

// ---------------- merged layer-1 gather (heavy-first), ee-precomputed, all-bf16 operands ----------------
__global__ __launch_bounds__(512) void gather1M(const int* __restrict__ lightL, const int* __restrict__ heavyL,
    const int* __restrict__ cnts, const int* __restrict__ offs, const int2* __restrict__ edata,
    const float2* __restrict__ eeb,
    const unsigned short* __restrict__ srcb, const unsigned short* __restrict__ dstb,
    const unsigned short* __restrict__ relpb,
    unsigned short* __restrict__ xbf) {
  __shared__ float part[8][208];
  int w = threadIdx.x >> 6, lane = threadIdx.x & 63;
  bool act = lane < 50;
  int cb = lane * 4;
  float a0 = 0.f, a1 = 0.f, a2v = 0.f, a3 = 0.f, rs0 = 0.f, rs1 = 0.f;
  bool hd0 = (cb < 100);
  auto edgeop = [&](int2 ed, float2 ev) {
    int e1 = ed.x & 0xFFFF;
    int t1 = ((unsigned)ed.x) >> 16;
    int t2f = ed.y & 0x1FF;
    rs0 += ev.x; rs1 += ev.y;
    if (act) {
      ushort4 dv = *(const ushort4*)(dstb + (size_t)e1 * 200 + cb);
      ushort4 rv = *(const ushort4*)(relpb + (size_t)t1 * 200 + cb);
      float m0 = b2f(dv.x) + b2f(rv.x);
      float m1 = b2f(dv.y) + b2f(rv.y);
      float m2 = b2f(dv.z) + b2f(rv.z);
      float m3 = b2f(dv.w) + b2f(rv.w);
      if (t2f) {
        ushort4 r2 = *(const ushort4*)(relpb + (size_t)(t2f - 1) * 200 + cb);
        m0 += b2f(r2.x); m1 += b2f(r2.y); m2 += b2f(r2.z); m3 += b2f(r2.w);
      }
      float ee = hd0 ? ev.x : ev.y;
      a0 += ee * m0; a1 += ee * m1; a2v += ee * m2; a3 += ee * m3;
    }
  };
  if (blockIdx.x < HBMAX) {
    int hidx = blockIdx.x;
    if (hidx >= cnts[1]) return;
    int node = heavyL[hidx];
    int s = offs[node], e = offs[node + 1];
    int q = s + w;
    for (; q + 8 < e; q += 16) { edgeop(edata[q], eeb[q]); edgeop(edata[q + 8], eeb[q + 8]); }
    if (q < e) edgeop(edata[q], eeb[q]);
    if (act) { part[w][cb] = a0; part[w][cb + 1] = a1; part[w][cb + 2] = a2v; part[w][cb + 3] = a3; }
    if (lane == 0) { part[w][200] = rs0; part[w][201] = rs1; }
    __syncthreads();
    int t = threadIdx.x;
    if (t < 224) {
      unsigned short outv = 0;
      if (t < 200) {
        float a = 0.f, r0 = 0.f, r1 = 0.f;
        #pragma unroll
        for (int wv = 0; wv < 8; ++wv) { a += part[wv][t]; r0 += part[wv][200]; r1 += part[wv][201]; }
        float inv = (t < 100) ? 1.f / r0 : 1.f / r1;
        float v = b2f(srcb[(size_t)node * 200 + t]) + a * inv;
        v = (v > 0.f) ? v : expm1f(v);
        outv = bf16rne(v);
      }
      xbf[(size_t)node * 224 + t] = outv;
    }
    return;
  }
  int widx = (blockIdx.x - HBMAX) * 8 + w;
  if (widx >= cnts[0]) return;
  int node = lightL[widx];
  int s = offs[node], e = offs[node + 1];
  int q = s;
  for (; q + 1 < e; q += 2) { edgeop(edata[q], eeb[q]); edgeop(edata[q + 1], eeb[q + 1]); }
  if (q < e) edgeop(edata[q], eeb[q]);
  bool has = (e > s);
  unsigned short* xo = xbf + (size_t)node * 224;
  if (act) {
    float inv = has ? (hd0 ? 1.f / rs0 : 1.f / rs1) : 0.f;
    ushort4 sv = *(const ushort4*)(srcb + (size_t)node * 200 + cb);
    float v0 = has ? b2f(sv.x) + a0 * inv : 0.f;
    float v1 = has ? b2f(sv.y) + a1 * inv : 0.f;
    float v2 = has ? b2f(sv.z) + a2v * inv : 0.f;
    float v3 = has ? b2f(sv.w) + a3 * inv : 0.f;
    v0 = (v0 > 0.f) ? v0 : expm1f(v0);
    v1 = (v1 > 0.f) ? v1 : expm1f(v1);
    v2 = (v2 > 0.f) ? v2 : expm1f(v2);
    v3 = (v3 > 0.f) ? v3 : expm1f(v3);
    ushort4 ov = {bf16rne(v0), bf16rne(v1), bf16rne(v2), bf16rne(v3)};
    *(ushort4*)(xo + cb) = ov;
  } else if (lane < 56) {
    ushort4 z = {0, 0, 0, 0};
    *(ushort4*)(xo + cb) = z;
  }
}

// ---------------- merged layer-2 gather (heavy-first), ee-precomputed, bf16 out ----------------
__global__ __launch_bounds__(512) void gather2M(const int* __restrict__ lightL, const int* __restrict__ heavyL,
    const int* __restrict__ cnts, const int* __restrict__ offs, const int2* __restrict__ edata,
    const float* __restrict__ eeb,
    const unsigned short* __restrict__ srcb, const unsigned short* __restrict__ dstb,
    const unsigned short* __restrict__ relpb,
    unsigned short* __restrict__ h2b) {
  __shared__ float part[8][208];
  int w = threadIdx.x >> 6, lane = threadIdx.x & 63;
  bool act = lane < 50;
  int cb = lane * 4;
  float a0 = 0.f, a1 = 0.f, a2v = 0.f, a3 = 0.f, rs = 0.f;
  auto edgeop = [&](int2 ed, float ee) {
    int e1 = ed.x & 0xFFFF;
    int t1 = ((unsigned)ed.x) >> 16;
    int t2f = ed.y & 0x1FF;
    rs += ee;
    if (act) {
      ushort4 dv = *(const ushort4*)(dstb + (size_t)e1 * 200 + cb);
      ushort4 rv = *(const ushort4*)(relpb + (size_t)t1 * 200 + cb);
      float m0 = b2f(dv.x) + b2f(rv.x);
      float m1 = b2f(dv.y) + b2f(rv.y);
      float m2 = b2f(dv.z) + b2f(rv.z);
      float m3 = b2f(dv.w) + b2f(rv.w);
      if (t2f) {
        ushort4 r2 = *(const ushort4*)(relpb + (size_t)(t2f - 1) * 200 + cb);
        m0 += b2f(r2.x); m1 += b2f(r2.y); m2 += b2f(r2.z); m3 += b2f(r2.w);
      }
      a0 += ee * m0; a1 += ee * m1; a2v += ee * m2; a3 += ee * m3;
    }
  };
  if (blockIdx.x < HBMAX) {
    int hidx = blockIdx.x;
    if (hidx >= cnts[1]) return;
    int node = heavyL[hidx];
    int s = offs[node], e = offs[node + 1];
    int q = s + w;
    for (; q + 8 < e; q += 16) { edgeop(edata[q], eeb[q]); edgeop(edata[q + 8], eeb[q + 8]); }
    if (q < e) edgeop(edata[q], eeb[q]);
    if (act) { part[w][cb] = a0; part[w][cb + 1] = a1; part[w][cb + 2] = a2v; part[w][cb + 3] = a3; }
    if (lane == 0) part[w][200] = rs;
    __syncthreads();
    int t = threadIdx.x;
    if (t < 200) {
      float a = 0.f, r = 0.f;
      #pragma unroll
      for (int wv = 0; wv < 8; ++wv) { a += part[wv][t]; r += part[wv][200]; }
      float v = b2f(srcb[(size_t)node * 200 + t]) + a / r;
      v = (v > 0.f) ? v : expm1f(v);
      h2b[(size_t)node * 200 + t] = bf16rne(v);
    }
    return;
  }
  int widx = (blockIdx.x - HBMAX) * 8 + w;
  if (widx >= cnts[0]) return;
  int node = lightL[widx];
  int s = offs[node], e = offs[node + 1];
  int q = s;
  for (; q + 1 < e; q += 2) { edgeop(edata[q], eeb[q]); edgeop(edata[q + 1], eeb[q + 1]); }
  if (q < e) edgeop(edata[q], eeb[q]);
  if (!act) return;
  bool has = (e > s);
  float inv = has ? 1.f / rs : 0.f;
  ushort4 sv = *(const ushort4*)(srcb + (size_t)node * 200 + cb);
  float v0 = has ? b2f(sv.x) + a0 * inv : 0.f;
  float v1 = has ? b2f(sv.y) + a1 * inv : 0.f;
  float v2 = has ? b2f(sv.z) + a2v * inv : 0.f;
  float v3 = has ? b2f(sv.w) + a3 * inv : 0.f;
  v0 = (v0 > 0.f) ? v0 : expm1f(v0);
  v1 = (v1 > 0.f) ? v1 : expm1f(v1);
  v2 = (v2 > 0.f) ? v2 : expm1f(v2);
  v3 = (v3 > 0.f) ? v3 : expm1f(v3);
  ushort4 ov = {bf16rne(v0), bf16rne(v1), bf16rne(v2), bf16rne(v3)};
  *(ushort4*)(h2b + (size_t)node * 200 + cb) = ov;
}

// ---------------- final: out = l2norm(xw + mask*h2), blocked lanes ----------------
__global__ __launch_bounds__(256) void finalk2(const float* __restrict__ xw,
                                               const unsigned short* __restrict__ h2b,
                                               const float* __restrict__ maskA, float* __restrict__ out) {
  int row  = blockIdx.x * 4 + (threadIdx.x >> 6);
  int lane = threadIdx.x & 63;
  if (row >= NN) return;
  bool act = lane < 50;
  int cb = lane * 4;
  float m = maskA[row];
  float v0 = 0.f, v1 = 0.f, v2 = 0.f, v3 = 0.f;
  if (act) {
    float4 xv = *(const float4*)(xw + (size_t)row * 200 + cb);
    ushort4 hv = *(const ushort4*)(h2b + (size_t)row * 200 + cb);
    v0 = xv.x + m * b2f(hv.x);
    v1 = xv.y + m * b2f(hv.y);
    v2 = xv.z + m * b2f(hv.z);
    v3 = xv.w + m * b2f(hv.w);
  }
  float ss = v0 * v0 + v1 * v1 + v2 * v2 + v3 * v3;
  #pragma unroll
  for (int off = 1; off < 64; off <<= 1) ss += __shfl_xor(ss, off);
  float inv = 1.f / fmaxf(sqrtf(ss), 1e-12f);
  if (act) {
    float4 ov = {v0 * inv, v1 * inv, v2 * inv, v3 * inv};
    *(float4*)(out + (size_t)row * 200 + cb) = ov;
  }
}

extern "C" void kernel_launch(void* const* d_in, const int* in_sizes, int n_in,
                              void* d_out, int out_size, void* d_ws, size_t ws_size,
                              hipStream_t stream) {
  (void)in_sizes; (void)n_in; (void)out_size; (void)ws_size;
  const float* ent      = (const float*)d_in[0];
  const float* rel      = (const float*)d_in[1];
  const float* a_heads  = (const float*)d_in[3];
  const float* a2_heads = (const float*)d_in[4];
  const float* W_gat    = (const float*)d_in[5];
  const float* a_out    = (const float*)d_in[6];
  const float* a2_out   = (const float*)d_in[7];
  const float* W_ent    = (const float*)d_in[8];
  const int* edge_list  = (const int*)d_in[9];
  const int* edge_type  = (const int*)d_in[10];
  const int* tin        = (const int*)d_in[11];
  const int* binp       = (const int*)d_in[12];

  float* out    = (float*)d_out;
  float* outrel = out + 10000000;     // (500,200) output 1

  float* ws = (float*)d_ws;
  unsigned short* bufSb  = (unsigned short*)ws;                // NN*200 bf16: srcp1 -> srcp2
  unsigned short* dstD   = (unsigned short*)(ws + 5000000);    // NN*200 bf16: dstp1 -> dstp2
  unsigned short* relp1b = (unsigned short*)(ws + 10000000);   // 100k bf16
  unsigned short* relp2b = (unsigned short*)(ws + 10050000);
  float* ssrc1 = ws + 10100000;       // N*2
  float* sdst1 = ws + 10200000;       // N*2
  float* s2src = ws + 10300000;       // N
  float* s2dst = ws + 10350000;       // N
  float* srel1 = ws + 10400000;       // 1000
  float* s2rel = ws + 10402000;       // 500
  float* maskA = ws + 10404000;       // N
  unsigned short* h2b   = (unsigned short*)(ws + 10460000);    // NN*200 bf16
  unsigned short* x0nbf = (unsigned short*)(ws + 15460000);    // MP*128 bf16
  unsigned short* xbf   = (unsigned short*)(ws + 18700000);    // MP*224 bf16
  unsigned short* B1s   = (unsigned short*)(ws + 24310000);    // 208*128
  unsigned short* B1d   = (unsigned short*)(ws + 24325000);
  unsigned short* Brel1 = (unsigned short*)(ws + 24340000);
  unsigned short* Bxw   = (unsigned short*)(ws + 24355000);
  unsigned short* Bwgat = (unsigned short*)(ws + 24370000);
  unsigned short* B2s   = (unsigned short*)(ws + 24385000);    // 208*224
  unsigned short* B2d   = (unsigned short*)(ws + 24410000);
  unsigned short* B2rel = (unsigned short*)(ws + 24435000);
  unsigned short* relbf = (unsigned short*)(ws + 24460000);    // 512*128
  unsigned short* orelb = (unsigned short*)(ws + 24495000);    // 512*224
  float2* eeb1 = (float2*)(ws + 24555000);   // ETOT float2
  float*  eeb2 = ws + 25305000;              // ETOT float
  int* ibase  = (int*)(ws + 25700000);
  int* deg    = ibase;                // 50k
  int* offs   = ibase + 50000;        // 50k+1
  int* pos    = ibase + 100016;       // 50k
  int* bsum   = ibase + 150016;       // 256
  int* cnts   = ibase + 150272;       // 2 (+pad)
  int* lightL = ibase + 150280;       // 50k
  int* heavyL = ibase + 200280;       // 50k (+pad)
  int2* edata = (int2*)(ibase + 250288); // 375k int2

  hipMemsetAsync(deg,   0, (size_t)NN * 4, stream);
  hipMemsetAsync(maskA, 0, (size_t)NN * 4, stream);
  hipMemsetAsync(cnts,  0, 8, stream);
  hipMemsetAsync(orelb, 0, (size_t)512 * 224 * 2, stream);

  // l2norm + histk
  {
    dim3 g(12512, 2);
    startk<<<g, 256, 0, stream>>>(ent, x0nbf, edge_list, tin, deg);
  }
  scanA<<<196, 256, 0, stream>>>(deg, bsum, NN);
  scanB<<<1, 256, 0, stream>>>(bsum, 196);
  scanC<<<196, 256, 0, stream>>>(deg, bsum, offs, pos, NN, ETOT);
  {
    dim3 g(1465, 2);
    scatBuild<<<g, 256, 0, stream>>>(edge_list, edge_type, tin, offs, pos, edata,
                                     lightL, heavyL, cnts);
  }
  {
    dim3 g(256, 9);
    convAll<<<g, 256, 0, stream>>>(rel, a_heads, W_ent, W_gat, a_out,
                                   B1s, B1d, Brel1, Bxw, Bwgat, B2s, B2d, B2rel, relbf);
  }

  // layer-1 projections + xw + rel projections + out_relation_1, one 5-job launch
  {
    GJob js    = {x0nbf, NN,    B1s,   nullptr, bufSb,  200, a2_heads, ssrc1, 1};
    GJob jd    = {x0nbf, NN,    B1d,   nullptr, dstD,   200, a2_heads, sdst1, 1};
    GJob jx    = {x0nbf, NN,    Bxw,   out,     nullptr, 0,  nullptr,  nullptr, 0};
    GJob jrel1 = {relbf, NRELS, Brel1, nullptr, relp1b, 200, a2_heads, srel1, 1};
    GJob jorel = {relbf, NRELS, Bwgat, outrel,  orelb,  224, nullptr,  nullptr, 0};
    dim3 g(782, 5);
    gemm_multi<128><<<g, 256, 0, stream>>>(js, jd, jx, jrel1, jorel);
  }

  // edgeEE1 + padx + maskset
  {
    dim3 g(1465, 2);
    eeMisc1<<<g, 256, 0, stream>>>(edata, ssrc1, sdst1, srel1, eeb1, xbf, binp, maskA);
  }

  gather1M<<<HBMAX + LB1, 512, 0, stream>>>(lightL, heavyL, cnts, offs, edata, eeb1,
                                            bufSb, dstD, relp1b, xbf);

  // layer-2 projections + relp2, one 3-job launch
  {
    GJob js    = {xbf,   NN,    B2s,   nullptr, bufSb,  200, a2_out, s2src, 2};
    GJob jd    = {xbf,   NN,    B2d,   nullptr, dstD,   200, a2_out, s2dst, 2};
    GJob jrp2  = {orelb, NRELS, B2rel, nullptr, relp2b, 200, a2_out, s2rel, 2};
    GJob jz    = {nullptr, 0, nullptr, nullptr, nullptr, 0, nullptr, nullptr, 0};
    dim3 g(782, 3);
    gemm_multi<224><<<g, 256, 0, stream>>>(js, jd, jrp2, jz, jz);
  }

  edgeEE2<<<(ETOT + 255) / 256, 256, 0, stream>>>(edata, s2src, s2dst, s2rel, eeb2);

  gather2M<<<HBMAX + LB1, 512, 0, stream>>>(lightL, heavyL, cnts, offs, edata, eeb2,
                                            bufSb, dstD, relp2b, h2b);

  finalk2<<<12500, 256, 0, stream>>>(out, h2b, maskA, out);
}

// Round 13
// 369.943 us; speedup vs baseline: 1.6660x; 1.0548x over previous
//
#include <hip/hip_runtime.h>
#include <math.h>

#define NN    50000
#define MP    50048    // padded rows (782*64)
#define NEDGE 250000
#define NHOPE 125000
#define ETOT  375000
#define NRELS 500
#define BATCH 65536
#define LB1   6250     // light blocks (8 waves each -> 50000 waves)
#define HBMAX 5769     // max heavy nodes (deg>64): 375000/65

typedef __attribute__((ext_vector_type(8))) short bf16x8;
typedef __attribute__((ext_vector_type(4))) float f32x4;

__device__ __forceinline__ unsigned short bf16rne(float f) {
  unsigned u = __float_as_uint(f);
  unsigned r = (u + 0x7FFFu + ((u >> 16) & 1u)) >> 16;
  return (unsigned short)r;
}
__device__ __forceinline__ float b2f(unsigned short u) {
  return __uint_as_float(((unsigned)u) << 16);
}

struct GJob {
  const unsigned short* A;   // padded rows x KP bf16
  int M;                     // valid rows
  const unsigned short* B;   // 208 x KP bf16
  float* Cf;                 // f32 out (ld 200) or null
  unsigned short* Cbf;       // bf16 out (ld ldcb) or null
  int ldcb;
  const float* a2;           // 200 floats or null
  float* dot;                // per-row scalar(s) or null
  int dotmode;               // 1 = split at 100, 2 = single sum
};

// ---------------- fused: l2norm (y=0) + histk (y=1) + weight conversions (y=2) ----------------
__global__ __launch_bounds__(256) void startk(const float* __restrict__ in,
                                              unsigned short* __restrict__ out,
                                              const int* __restrict__ el, const int* __restrict__ tin,
                                              int* __restrict__ deg,
                                              const float* __restrict__ rel,
                                              const float* __restrict__ ah,
                                              const float* __restrict__ W_ent,
                                              const float* __restrict__ W_gat,
                                              const float* __restrict__ a_out,
                                              unsigned short* __restrict__ B1s,
                                              unsigned short* __restrict__ B1d,
                                              unsigned short* __restrict__ Brel1,
                                              unsigned short* __restrict__ Bxw,
                                              unsigned short* __restrict__ Bwgat,
                                              unsigned short* __restrict__ B2s,
                                              unsigned short* __restrict__ B2d,
                                              unsigned short* __restrict__ B2rel,
                                              unsigned short* __restrict__ relbf) {
  if (blockIdx.y == 1) {
    int i = blockIdx.x * 256 + threadIdx.x;
    if (i < ETOT) {
      int e0 = (i < NEDGE) ? el[i] : tin[(size_t)(i - NEDGE) * 4 + 3];
      atomicAdd(&deg[e0], 1);
    }
    return;
  }
  if (blockIdx.y == 2) {
    const int S1 = 26624, S2 = 46592;   // 208*128, 208*224
    int idx = blockIdx.x * 256 + threadIdx.x;
    if (idx < 3 * S1) {                 // B1s / B1d / Brel1
      int y = idx / S1, r = idx - y * S1;
      int j = r >> 7, k = r & 127;
      float v = 0.f;
      if (j < 200 && k < 100)
        v = ah[((j < 100) ? 0 : 30000) + (j % 100) * 300 + y * 100 + k];
      (y == 0 ? B1s : (y == 1 ? B1d : Brel1))[r] = bf16rne(v);
    } else if (idx < 4 * S1) {          // Bxw : W_ent^T
      int r = idx - 3 * S1;
      int j = r >> 7, k = r & 127;
      float v = (j < 200 && k < 100) ? W_ent[(size_t)k * 200 + j] : 0.f;
      Bxw[r] = bf16rne(v);
    } else if (idx < 5 * S1) {          // Bwgat : W_gat^T
      int r = idx - 4 * S1;
      int j = r >> 7, k = r & 127;
      float v = (j < 200 && k < 100) ? W_gat[(size_t)k * 200 + j] : 0.f;
      Bwgat[r] = bf16rne(v);
    } else if (idx < 5 * S1 + 3 * S2) { // B2s / B2d / B2rel
      int r = idx - 5 * S1;
      int y = r / S2; r -= y * S2;
      int j = r / 224, k = r - j * 224;
      float v = (j < 200 && k < 200) ? a_out[(size_t)j * 600 + y * 200 + k] : 0.f;
      (y == 0 ? B2s : (y == 1 ? B2d : B2rel))[r] = bf16rne(v);
    } else if (idx < 5 * S1 + 3 * S2 + 65536) {  // relbf 512x128
      int r = idx - 5 * S1 - 3 * S2;
      int j = r >> 7, k = r & 127;
      float v = (j < 500 && k < 100) ? rel[(size_t)j * 100 + k] : 0.f;
      relbf[r] = bf16rne(v);
    }
    return;
  }
  int row  = blockIdx.x * 4 + (threadIdx.x >> 6);
  int lane = threadIdx.x & 63;
  if (row >= MP) return;
  unsigned short* o = out + (size_t)row * 128;
  if (row >= NN) { o[lane] = 0; o[lane + 64] = 0; return; }
  const float* r = in + (size_t)row * 100;
  float v0 = r[lane];
  float v1 = (lane + 64 < 100) ? r[lane + 64] : 0.f;
  float ss = v0 * v0 + v1 * v1;
  #pragma unroll
  for (int off = 1; off < 64; off <<= 1) ss += __shfl_xor(ss, off);
  float inv = 1.f / fmaxf(sqrtf(ss), 1e-12f);
  o[lane] = bf16rne(v0 * inv);
  o[lane + 64] = (lane + 64 < 100) ? bf16rne(v1 * inv) : (unsigned short)0;
}

// ---------------- multi-job bf16 MFMA GEMM, LDS-staged B, LDS-coalesced epilogue ----------------
template<int KP>
__global__ __launch_bounds__(256) void gemm_multi(GJob j0, GJob j1, GJob j2, GJob j3, GJob j4) {
  __shared__ __attribute__((aligned(16))) char smem[54272];
  unsigned short* shb = (unsigned short*)smem;
  float (*clds)[16][212] = (float (*)[16][212])smem;   // [4][16][212]
  GJob jb = (blockIdx.y == 0) ? j0 : (blockIdx.y == 1) ? j1 : (blockIdx.y == 2) ? j2
          : (blockIdx.y == 3) ? j3 : j4;
  if (blockIdx.x * 64 >= jb.M) return;
  int wv = threadIdx.x >> 6, lane = threadIdx.x & 63;
  int rbw = blockIdx.x * 64 + wv * 16;
  int rl = lane & 15;
  int kq = (lane >> 4) * 8;
  const unsigned short* ap = jb.A + (size_t)(rbw + rl) * KP + kq;
  f32x4 acc[13];
  #pragma unroll
  for (int t = 0; t < 13; ++t) acc[t] = (f32x4){0.f, 0.f, 0.f, 0.f};
  constexpr int NST = (KP + 63) / 64;
  #pragma unroll
  for (int s = 0; s < NST; ++s) {
    const int ks0 = s * 64;
    const int sw  = (KP - ks0 >= 64) ? 64 : (KP - ks0);
    const int cpr = sw / 8;
    __syncthreads();
    for (int idx = threadIdx.x; idx < 208 * cpr; idx += 256) {
      int row = idx / cpr, cw = idx - row * cpr;
      *(float4*)(shb + row * 72 + cw * 8) =
          *(const float4*)(jb.B + (size_t)row * KP + ks0 + cw * 8);
    }
    __syncthreads();
    for (int ksl = 0; ksl < sw; ksl += 32) {
      bf16x8 a0 = *(const bf16x8*)(ap + ks0 + ksl);
      const unsigned short* bl = shb + (size_t)rl * 72 + kq + ksl;
      #pragma unroll
      for (int t = 0; t < 13; ++t) {
        bf16x8 b = *(const bf16x8*)(bl + t * 16 * 72);
        acc[t] = __builtin_amdgcn_mfma_f32_16x16x32_bf16(a0, b, acc[t], 0, 0, 0);
      }
    }
  }
  int rg = (lane >> 4) * 4;
  if (jb.dot) {
    float p0[4] = {0.f, 0.f, 0.f, 0.f}, p1[4] = {0.f, 0.f, 0.f, 0.f};
    #pragma unroll
    for (int t = 0; t < 13; ++t) {
      int col = t * 16 + rl;
      float av = (col < 200) ? jb.a2[col] : 0.f;
      bool lo = (col < 100);
      #pragma unroll
      for (int g = 0; g < 4; ++g) {
        float v = acc[t][g] * av;
        if (lo) p0[g] += v; else p1[g] += v;
      }
    }
    #pragma unroll
    for (int off = 1; off < 16; off <<= 1) {
      #pragma unroll
      for (int g = 0; g < 4; ++g) {
        p0[g] += __shfl_xor(p0[g], off);
        p1[g] += __shfl_xor(p1[g], off);
      }
    }
    if (rl == 0) {
      #pragma unroll
      for (int g = 0; g < 4; ++g) {
        int row = rbw + rg + g;
        if (row < jb.M) {
          if (jb.dotmode == 1) { jb.dot[row * 2] = p0[g]; jb.dot[row * 2 + 1] = p1[g]; }
          else                 { jb.dot[row] = p0[g] + p1[g]; }
        }
      }
    }
  }
  if (jb.Cf || jb.Cbf) {
    __syncthreads();
    #pragma unroll
    for (int t = 0; t < 13; ++t) {
      #pragma unroll
      for (int g = 0; g < 4; ++g)
        clds[wv][rg + g][t * 16 + rl] = acc[t][g];
    }
    __syncthreads();
    #pragma unroll
    for (int i = 0; i < 13; ++i) {
      int idx = i * 64 + lane;
      if (idx < 800) {
        int r = idx / 50, cw = idx - r * 50;
        float4 v = *(const float4*)&clds[wv][r][cw * 4];
        int grow = rbw + r;
        if (grow < jb.M) {
          if (jb.Cf)
            *(float4*)(jb.Cf + (size_t)grow * 200 + cw * 4) = v;
          if (jb.Cbf) {
            ushort4 o = {bf16rne(v.x), bf16rne(v.y), bf16rne(v.z), bf16rne(v.w)};
            *(ushort4*)(jb.Cbf + (size_t)grow * jb.ldcb + cw * 4) = o;
          }
        }
      }
    }
  }
}

// ---------------- CSR scans ----------------
__global__ __launch_bounds__(256) void scanA(const int* __restrict__ deg, int* __restrict__ bsum, int n) {
  __shared__ int s[256];
  int t = threadIdx.x;
  int i = blockIdx.x * 256 + t;
  s[t] = (i < n) ? deg[i] : 0;
  __syncthreads();
  for (int off = 128; off > 0; off >>= 1) {
    if (t < off) s[t] += s[t + off];
    __syncthreads();
  }
  if (t == 0) bsum[blockIdx.x] = s[0];
}

// scanC with inline bsum prefix (no scanB)
__global__ __launch_bounds__(256) void scanC(const int* __restrict__ deg, const int* __restrict__ bsum,
                                             int* __restrict__ offs, int* __restrict__ pos, int n, int total) {
  __shared__ int sb[256];
  __shared__ int s[256];
  int t = threadIdx.x;
  sb[t] = (t < 196) ? bsum[t] : 0;
  __syncthreads();
  for (int off = 1; off < 256; off <<= 1) {
    int add = (t >= off) ? sb[t - off] : 0;
    __syncthreads();
    sb[t] += add;
    __syncthreads();
  }
  int base = (blockIdx.x == 0) ? 0 : sb[blockIdx.x - 1];
  int i = blockIdx.x * 256 + t;
  int v = (i < n) ? deg[i] : 0;
  s[t] = v;
  __syncthreads();
  for (int off = 1; off < 256; off <<= 1) {
    int add = (t >= off) ? s[t - off] : 0;
    __syncthreads();
    s[t] += add;
    __syncthreads();
  }
  if (i < n) {
    int e = base + s[t] - v;
    offs[i] = e;
    pos[i]  = e;
  }
  if (i == 0) offs[n] = total;
}

// fused: scatterk (y=0) + buildLists (y=1). edata: .x = e1|(t1<<16), .y = t2f|(e0<<9)
__global__ __launch_bounds__(256) void scatBuild(const int* __restrict__ el, const int* __restrict__ et,
                                                 const int* __restrict__ tin, const int* __restrict__ offs,
                                                 int* __restrict__ pos, int2* __restrict__ edata,
                                                 int* __restrict__ lightL, int* __restrict__ heavyL,
                                                 int* __restrict__ cnts) {
  if (blockIdx.y == 0) {
    int i = blockIdx.x * 256 + threadIdx.x;
    if (i >= ETOT) return;
    int e0, e1, t1, t2f;
    if (i < NEDGE) {
      e0 = el[i]; e1 = el[NEDGE + i]; t1 = et[i]; t2f = 0;
    } else {
      const int* q = tin + (size_t)(i - NEDGE) * 4;
      e0 = q[3]; e1 = q[0]; t1 = q[1]; t2f = q[2] + 1;
    }
    int slot = atomicAdd(&pos[e0], 1);
    edata[slot] = make_int2(e1 | (t1 << 16), t2f | (e0 << 9));
    return;
  }
  int i = blockIdx.x * 256 + threadIdx.x;
  int lane = threadIdx.x & 63;
  bool valid = (i < NN);
  int d = valid ? (offs[i + 1] - offs[i]) : 0;
  bool heavy = valid && (d > 64);
  bool light = valid && (d <= 64);
  unsigned long long mh = __ballot(heavy);
  unsigned long long ml = __ballot(light);
  unsigned long long below = (1ULL << lane) - 1ULL;
  int bh = 0, bl = 0;
  if (lane == 0) {
    if (mh) bh = atomicAdd(&cnts[1], __popcll(mh));
    if (ml) bl = atomicAdd(&cnts[0], __popcll(ml));
  }
  bh = __shfl(bh, 0);
  bl = __shfl(bl, 0);
  if (heavy) heavyL[bh + __popcll(mh & below)] = i;
  if (light) lightL[bl + __popcll(ml & below)] = i;
}

// ---------------- fused: edgeEE1 (y=0) + padx/maskset (y=1) ----------------
__global__ __launch_bounds__(256) void eeMisc1(const int2* __restrict__ edata,
                                               const float* __restrict__ ssrc,
                                               const float* __restrict__ sdst,
                                               const float* __restrict__ srel,
                                               float2* __restrict__ ee,
                                               unsigned short* __restrict__ xbf,
                                               const int* __restrict__ bi,
                                               float* __restrict__ maskA) {
  if (blockIdx.y == 1) {
    if (blockIdx.x < 42) {
      int i = blockIdx.x * 256 + threadIdx.x;
      if (i < (MP - NN) * 224) xbf[(size_t)NN * 224 + i] = 0;
    } else if (blockIdx.x < 42 + 256) {
      int t = (blockIdx.x - 42) * 256 + threadIdx.x;
      if (t < BATCH) maskA[bi[t * 3 + 2]] = 1.0f;
    }
    return;
  }
  int q = blockIdx.x * 256 + threadIdx.x;
  if (q >= ETOT) return;
  int2 ed = edata[q];
  int e1 = ed.x & 0xFFFF;
  int t1 = ((unsigned)ed.x) >> 16;
  int t2f = ed.y & 0x1FF;
  int e0 = ((unsigned)ed.y) >> 9;
  float p0 = ssrc[e0 * 2]     + sdst[e1 * 2]     + srel[t1 * 2];
  float p1 = ssrc[e0 * 2 + 1] + sdst[e1 * 2 + 1] + srel[t1 * 2 + 1];
  if (t2f) { int t2 = t2f - 1; p0 += srel[t2 * 2]; p1 += srel[t2 * 2 + 1]; }
  p0 = (p0 > 0.f) ? p0 : 0.2f * p0;
  p1 = (p1 > 0.f) ? p1 : 0.2f * p1;
  ee[q] = make_float2(__expf(-p0), __expf(-p1));
}

__global__ __launch_bounds__(256) void edgeEE2(const int2* __restrict__ edata,
                                               const float* __restrict__ ssrc,
                                               const float* __restrict__ sdst,
                                               const float* __restrict__ srel,
                                               float* __restrict__ ee) {
  int q = blockIdx.x * 256 + threadIdx.x;
  if (q >= ETOT) return;
  int2 ed = edata[q];
  int e1 = ed.x & 0xFFFF;
  int t1 = ((unsigned)ed.x) >> 16;
  int t2f = ed.y & 0x1FF;
  int e0 = ((unsigned)ed.y) >> 9;
  float p = ssrc[e0] + sdst[e1] + srel[t1];
  if (t2f) p += srel[t2f - 1];
  p = (p > 0.f) ? p : 0.2f * p;
  ee[q] = __expf(-p);
}

// ---------------- merged layer-1 gather ----------------
__global__ __launch_bounds__(512) void gather1M(const int* __restrict__ lightL, const int* __restrict__ heavyL,
    const int* __restrict__ cnts, const int* __restrict__ offs, const int2* __restrict__ edata,
    const float2* __restrict__ eeb,
    const unsigned short* __restrict__ srcb, const unsigned short* __restrict__ dstb,
    const unsigned short* __restrict__ relpb,
    unsigned short* __restrict__ xbf) {
  __shared__ float part[8][208];
  int w = threadIdx.x >> 6, lane = threadIdx.x & 63;
  bool act = lane < 50;
  int cb = lane * 4;
  float a0 = 0.f, a1 = 0.f, a2v = 0.f, a3 = 0.f, rs0 = 0.f, rs1 = 0.f;
  bool hd0 = (cb < 100);
  auto edgeop = [&](int2 ed, float2 ev) {
    int e1 = ed.x & 0xFFFF;
    int t1 = ((unsigned)ed.x) >> 16;
    int t2f = ed.y & 0x1FF;
    rs0 += ev.x; rs1 += ev.y;
    if (act) {
      ushort4 dv = *(const ushort4*)(dstb + (size_t)e1 * 200 + cb);
      ushort4 rv = *(const ushort4*)(relpb + (size_t)t1 * 200 + cb);
      float m0 = b2f(dv.x) + b2f(rv.x);
      float m1 = b2f(dv.y) + b2f(rv.y);
      float m2 = b2f(dv.z) + b2f(rv.z);
      float m3 = b2f(dv.w) + b2f(rv.w);
      if (t2f) {
        ushort4 r2 = *(const ushort4*)(relpb + (size_t)(t2f - 1) * 200 + cb);
        m0 += b2f(r2.x); m1 += b2f(r2.y); m2 += b2f(r2.z); m3 += b2f(r2.w);
      }
      float ee = hd0 ? ev.x : ev.y;
      a0 += ee * m0; a1 += ee * m1; a2v += ee * m2; a3 += ee * m3;
    }
  };
  if (blockIdx.x < HBMAX) {
    int hidx = blockIdx.x;
    if (hidx >= cnts[1]) return;
    int node = heavyL[hidx];
    int s = offs[node], e = offs[node + 1];
    int q = s + w;
    for (; q + 8 < e; q += 16) { edgeop(edata[q], eeb[q]); edgeop(edata[q + 8], eeb[q + 8]); }
    if (q < e) edgeop(edata[q], eeb[q]);
    if (act) { part[w][cb] = a0; part[w][cb + 1] = a1; part[w][cb + 2] = a2v; part[w][cb + 3] = a3; }
    if (lane == 0) { part[w][200] = rs0; part[w][201] = rs1; }
    __syncthreads();
    int t = threadIdx.x;
    if (t < 224) {
      unsigned short outv = 0;
      if (t < 200) {
        float a = 0.f, r0 = 0.f, r1 = 0.f;
        #pragma unroll
        for (int wv = 0; wv < 8; ++wv) { a += part[wv][t]; r0 += part[wv][200]; r1 += part[wv][201]; }
        float inv = (t < 100) ? 1.f / r0 : 1.f / r1;
        float v = b2f(srcb[(size_t)node * 200 + t]) + a * inv;
        v = (v > 0.f) ? v : expm1f(v);
        outv = bf16rne(v);
      }
      xbf[(size_t)node * 224 + t] = outv;
    }
    return;
  }
  int widx = (blockIdx.x - HBMAX) * 8 + w;
  if (widx >= cnts[0]) return;
  int node = lightL[widx];
  int s = offs[node], e = offs[node + 1];
  int q = s;
  for (; q + 1 < e; q += 2) { edgeop(edata[q], eeb[q]); edgeop(edata[q + 1], eeb[q + 1]); }
  if (q < e) edgeop(edata[q], eeb[q]);
  bool has = (e > s);
  unsigned short* xo = xbf + (size_t)node * 224;
  if (act) {
    float inv = has ? (hd0 ? 1.f / rs0 : 1.f / rs1) : 0.f;
    ushort4 sv = *(const ushort4*)(srcb + (size_t)node * 200 + cb);
    float v0 = has ? b2f(sv.x) + a0 * inv : 0.f;
    float v1 = has ? b2f(sv.y) + a1 * inv : 0.f;
    float v2 = has ? b2f(sv.z) + a2v * inv : 0.f;
    float v3 = has ? b2f(sv.w) + a3 * inv : 0.f;
    v0 = (v0 > 0.f) ? v0 : expm1f(v0);
    v1 = (v1 > 0.f) ? v1 : expm1f(v1);
    v2 = (v2 > 0.f) ? v2 : expm1f(v2);
    v3 = (v3 > 0.f) ? v3 : expm1f(v3);
    ushort4 ov = {bf16rne(v0), bf16rne(v1), bf16rne(v2), bf16rne(v3)};
    *(ushort4*)(xo + cb) = ov;
  } else if (lane < 56) {
    ushort4 z = {0, 0, 0, 0};
    *(ushort4*)(xo + cb) = z;
  }
}

// ---------------- merged layer-2 gather with FUSED final (elu + mask + l2norm -> out) ----------------
__global__ __launch_bounds__(512) void gather2M(const int* __restrict__ lightL, const int* __restrict__ heavyL,
    const int* __restrict__ cnts, const int* __restrict__ offs, const int2* __restrict__ edata,
    const float* __restrict__ eeb,
    const unsigned short* __restrict__ srcb, const unsigned short* __restrict__ dstb,
    const unsigned short* __restrict__ relpb,
    const float* __restrict__ maskA, float* __restrict__ out) {
  __shared__ float part[8][208];
  __shared__ float red[512];
  int w = threadIdx.x >> 6, lane = threadIdx.x & 63;
  bool act = lane < 50;
  int cb = lane * 4;
  float a0 = 0.f, a1 = 0.f, a2v = 0.f, a3 = 0.f, rs = 0.f;
  auto edgeop = [&](int2 ed, float ee) {
    int e1 = ed.x & 0xFFFF;
    int t1 = ((unsigned)ed.x) >> 16;
    int t2f = ed.y & 0x1FF;
    rs += ee;
    if (act) {
      ushort4 dv = *(const ushort4*)(dstb + (size_t)e1 * 200 + cb);
      ushort4 rv = *(const ushort4*)(relpb + (size_t)t1 * 200 + cb);
      float m0 = b2f(dv.x) + b2f(rv.x);
      float m1 = b2f(dv.y) + b2f(rv.y);
      float m2 = b2f(dv.z) + b2f(rv.z);
      float m3 = b2f(dv.w) + b2f(rv.w);
      if (t2f) {
        ushort4 r2 = *(const ushort4*)(relpb + (size_t)(t2f - 1) * 200 + cb);
        m0 += b2f(r2.x); m1 += b2f(r2.y); m2 += b2f(r2.z); m3 += b2f(r2.w);
      }
      a0 += ee * m0; a1 += ee * m1; a2v += ee * m2; a3 += ee * m3;
    }
  };
  if (blockIdx.x < HBMAX) {
    int hidx = blockIdx.x;
    if (hidx >= cnts[1]) return;
    int node = heavyL[hidx];
    int s = offs[node], e = offs[node + 1];
    int q = s + w;
    for (; q + 8 < e; q += 16) { edgeop(edata[q], eeb[q]); edgeop(edata[q + 8], eeb[q + 8]); }
    if (q < e) edgeop(edata[q], eeb[q]);
    if (act) { part[w][cb] = a0; part[w][cb + 1] = a1; part[w][cb + 2] = a2v; part[w][cb + 3] = a3; }
    if (lane == 0) part[w][200] = rs;
    __syncthreads();
    int t = threadIdx.x;
    float m = maskA[node];
    float u = 0.f;
    if (t < 200) {
      float a = 0.f, r = 0.f;
      #pragma unroll
      for (int wv = 0; wv < 8; ++wv) { a += part[wv][t]; r += part[wv][200]; }
      float v = b2f(srcb[(size_t)node * 200 + t]) + a / r;
      v = (v > 0.f) ? v : expm1f(v);
      u = out[(size_t)node * 200 + t] + m * v;
    }
    red[t] = u * u;
    __syncthreads();
    #pragma unroll
    for (int off = 256; off > 0; off >>= 1) {
      if (t < off) red[t] += red[t + off];
      __syncthreads();
    }
    float inv = 1.f / fmaxf(sqrtf(red[0]), 1e-12f);
    if (t < 200) out[(size_t)node * 200 + t] = u * inv;
    return;
  }
  int widx = (blockIdx.x - HBMAX) * 8 + w;
  if (widx >= cnts[0]) return;
  int node = lightL[widx];
  int s = offs[node], e = offs[node + 1];
  int q = s;
  for (; q + 1 < e; q += 2) { edgeop(edata[q], eeb[q]); edgeop(edata[q + 1], eeb[q + 1]); }
  if (q < e) edgeop(edata[q], eeb[q]);
  bool has = (e > s);
  float m = maskA[node];
  float u0 = 0.f, u1 = 0.f, u2 = 0.f, u3 = 0.f;
  if (act) {
    float inv = has ? 1.f / rs : 0.f;
    ushort4 sv = *(const ushort4*)(srcb + (size_t)node * 200 + cb);
    float v0 = has ? b2f(sv.x) + a0 * inv : 0.f;
    float v1 = has ? b2f(sv.y) + a1 * inv : 0.f;
    float v2 = has ? b2f(sv.z) + a2v * inv : 0.f;
    float v3 = has ? b2f(sv.w) + a3 * inv : 0.f;
    v0 = (v0 > 0.f) ? v0 : expm1f(v0);
    v1 = (v1 > 0.f) ? v1 : expm1f(v1);
    v2 = (v2 > 0.f) ? v2 : expm1f(v2);
    v3 = (v3 > 0.f) ? v3 : expm1f(v3);
    float4 xv = *(const float4*)(out + (size_t)node * 200 + cb);
    u0 = xv.x + m * v0;
    u1 = xv.y + m * v1;
    u2 = xv.z + m * v2;
    u3 = xv.w + m * v3;
  }
  float ss = u0 * u0 + u1 * u1 + u2 * u2 + u3 * u3;
  #pragma unroll
  for (int off = 1; off < 64; off <<= 1) ss += __shfl_xor(ss, off);
  float inv = 1.f / fmaxf(sqrtf(ss), 1e-12f);
  if (act) {
    float4 ov = {u0 * inv, u1 * inv, u2 * inv, u3 * inv};
    *(float4*)(out + (size_t)node * 200 + cb) = ov;
  }
}

extern "C" void kernel_launch(void* const* d_in, const int* in_sizes, int n_in,
                              void* d_out, int out_size, void* d_ws, size_t ws_size,
                              hipStream_t stream) {
  (void)in_sizes; (void)n_in; (void)out_size; (void)ws_size;
  const float* ent      = (const float*)d_in[0];
  const float* rel      = (const float*)d_in[1];
  const float* a_heads  = (const float*)d_in[3];
  const float* a2_heads = (const float*)d_in[4];
  const float* W_gat    = (const float*)d_in[5];
  const float* a_out    = (const float*)d_in[6];
  const float* a2_out   = (const float*)d_in[7];
  const float* W_ent    = (const float*)d_in[8];
  const int* edge_list  = (const int*)d_in[9];
  const int* edge_type  = (const int*)d_in[10];
  const int* tin        = (const int*)d_in[11];
  const int* binp       = (const int*)d_in[12];

  float* out    = (float*)d_out;
  float* outrel = out + 10000000;     // (500,200) output 1

  float* ws = (float*)d_ws;
  unsigned short* bufSb  = (unsigned short*)ws;                // NN*200 bf16
  unsigned short* dstD   = (unsigned short*)(ws + 5000000);
  unsigned short* relp1b = (unsigned short*)(ws + 10000000);
  unsigned short* relp2b = (unsigned short*)(ws + 10050000);
  float* ssrc1 = ws + 10100000;
  float* sdst1 = ws + 10200000;
  float* s2src = ws + 10300000;
  float* s2dst = ws + 10350000;
  float* srel1 = ws + 10400000;
  float* s2rel = ws + 10402000;
  // ---- contiguous zero region ----
  float* maskA = ws + 10404000;                                 // 50k f32
  int*   deg   = (int*)(ws + 10454000);                         // 50k int
  int*   cnts  = (int*)(ws + 10504000);                         // 8 int
  unsigned short* orelb = (unsigned short*)(ws + 10504008);     // 512*224 ushort
  // zero region ends at ws + 10561352
  unsigned short* x0nbf = (unsigned short*)(ws + 10570000);     // MP*128
  unsigned short* xbf   = (unsigned short*)(ws + 13780000);     // MP*224
  unsigned short* B1s   = (unsigned short*)(ws + 19390000);
  unsigned short* B1d   = (unsigned short*)(ws + 19405000);
  unsigned short* Brel1 = (unsigned short*)(ws + 19420000);
  unsigned short* Bxw   = (unsigned short*)(ws + 19435000);
  unsigned short* Bwgat = (unsigned short*)(ws + 19450000);
  unsigned short* B2s   = (unsigned short*)(ws + 19465000);
  unsigned short* B2d   = (unsigned short*)(ws + 19490000);
  unsigned short* B2rel = (unsigned short*)(ws + 19515000);
  unsigned short* relbf = (unsigned short*)(ws + 19540000);     // 512*128
  float2* eeb1 = (float2*)(ws + 19580000);                      // ETOT float2
  float*  eeb2 = ws + 20330000;                                 // ETOT float
  int* ibase  = (int*)(ws + 20710000);
  int* offs   = ibase;                 // 50k+1
  int* pos    = ibase + 50016;
  int* bsum   = ibase + 100016;        // 256
  int* lightL = ibase + 100288;
  int* heavyL = ibase + 150288;
  int2* edata = (int2*)(ibase + 200288);

  hipMemsetAsync(maskA, 0, (size_t)(10561352 - 10404000) * 4, stream);

  // l2norm + histk + weight conversions
  {
    dim3 g(12512, 3);
    startk<<<g, 256, 0, stream>>>(ent, x0nbf, edge_list, tin, deg,
                                  rel, a_heads, W_ent, W_gat, a_out,
                                  B1s, B1d, Brel1, Bxw, Bwgat, B2s, B2d, B2rel, relbf);
  }
  scanA<<<196, 256, 0, stream>>>(deg, bsum, NN);
  scanC<<<196, 256, 0, stream>>>(deg, bsum, offs, pos, NN, ETOT);
  {
    dim3 g(1465, 2);
    scatBuild<<<g, 256, 0, stream>>>(edge_list, edge_type, tin, offs, pos, edata,
                                     lightL, heavyL, cnts);
  }

  // layer-1 projections + xw + rel projections + out_relation_1, one 5-job launch
  {
    GJob js    = {x0nbf, NN,    B1s,   nullptr, bufSb,  200, a2_heads, ssrc1, 1};
    GJob jd    = {x0nbf, NN,    B1d,   nullptr, dstD,   200, a2_heads, sdst1, 1};
    GJob jx    = {x0nbf, NN,    Bxw,   out,     nullptr, 0,  nullptr,  nullptr, 0};
    GJob jrel1 = {relbf, NRELS, Brel1, nullptr, relp1b, 200, a2_heads, srel1, 1};
    GJob jorel = {relbf, NRELS, Bwgat, outrel,  orelb,  224, nullptr,  nullptr, 0};
    dim3 g(782, 5);
    gemm_multi<128><<<g, 256, 0, stream>>>(js, jd, jx, jrel1, jorel);
  }

  // edgeEE1 + padx + maskset
  {
    dim3 g(1465, 2);
    eeMisc1<<<g, 256, 0, stream>>>(edata, ssrc1, sdst1, srel1, eeb1, xbf, binp, maskA);
  }

  gather1M<<<HBMAX + LB1, 512, 0, stream>>>(lightL, heavyL, cnts, offs, edata, eeb1,
                                            bufSb, dstD, relp1b, xbf);

  // layer-2 projections + relp2, one 3-job launch
  {
    GJob js    = {xbf,   NN,    B2s,   nullptr, bufSb,  200, a2_out, s2src, 2};
    GJob jd    = {xbf,   NN,    B2d,   nullptr, dstD,   200, a2_out, s2dst, 2};
    GJob jrp2  = {orelb, NRELS, B2rel, nullptr, relp2b, 200, a2_out, s2rel, 2};
    GJob jz    = {nullptr, 0, nullptr, nullptr, nullptr, 0, nullptr, nullptr, 0};
    dim3 g(782, 3);
    gemm_multi<224><<<g, 256, 0, stream>>>(js, jd, jrp2, jz, jz);
  }

  edgeEE2<<<(ETOT + 255) / 256, 256, 0, stream>>>(edata, s2src, s2dst, s2rel, eeb2);

  // gather2 with fused elu+mask+l2norm epilogue (in place on out)
  gather2M<<<HBMAX + LB1, 512, 0, stream>>>(lightL, heavyL, cnts, offs, edata, eeb2,
                                            bufSb, dstD, relp2b, maskA, out);
}